// Round 14
// baseline (242.159 us; speedup 1.0000x reference)
//
#include <hip/hip_runtime.h>
#include <hip/hip_bf16.h>
#include <cmath>

// ---------------------------------------------------------------------------
// GAT 2-layer forward.
// CSR build via 2-level bucketing (binned packed src|dl<<17; bhist zeroed by
// k_init -- no hipMemsetAsync graph node). Layer1: bf16 MFMA GEMM (32-row
// tile, x-only LDS staging, B hoisted) with fused alpha epilogue writing
// INTERLEAVED asd1[N][16] (one 64B sector per alpha gather) -> agg1 (max-free
// softmax, 8 nodes/wave, uint4 gather) fused with helu-bf16 + as2/ad2
// projection. Layer2: aggregate (bf16 agg out), then fp32 GEMM W2 + sigmoid.
// ---------------------------------------------------------------------------

#define BSH 9                 // 512 nodes per bucket; requires N <= 131072
#define BNN (1 << BSH)

typedef __attribute__((ext_vector_type(8))) short short8v;
typedef __attribute__((ext_vector_type(4))) float f32x4;

__device__ __forceinline__ float lrelu02(float v) { return v > 0.f ? v : 0.2f * v; }

__device__ __forceinline__ unsigned short f2b(float f) {
  union { float f; unsigned int i; } c; c.f = f;
  unsigned int r = c.i + 0x7FFFu + ((c.i >> 16) & 1u);   // RNE
  return (unsigned short)(r >> 16);
}
__device__ __forceinline__ float lo16(unsigned int u) {
  union { float f; unsigned int i; } c; c.i = u << 16; return c.f;
}
__device__ __forceinline__ float hi16(unsigned int u) {
  union { float f; unsigned int i; } c; c.i = u & 0xFFFF0000u; return c.f;
}

// ---- init: W1^T->bf16 (blocks 0-15), W2-proj + bhist zero (block 16) ------

__global__ __launch_bounds__(256) void k_init(const float* __restrict__ W1,
                                              unsigned short* __restrict__ w1t,
                                              const float* __restrict__ W2,
                                              const float* __restrict__ a2s,
                                              const float* __restrict__ a2d,
                                              float* __restrict__ w2as, float* __restrict__ w2ad,
                                              int* __restrict__ bhist, int K) {
  int b = blockIdx.x, t = threadIdx.x;
  if (b < 16) {
    int idx = b * 256 + t;                    // 0..4095
#pragma unroll
    for (int j = 0; j < 4; ++j) {
      int e = idx * 4 + j;                    // flat w1t index = col*256 + k
      int col = e >> 8, k = e & 255;
      w1t[e] = f2b(W1[k * 64 + col]);
    }
  } else {
    if (t <= K) bhist[t] = 0;
    if (t < 64) {
      float s = 0.f;
      for (int k = 0; k < 100; ++k) s += W2[t * 100 + k] * a2s[k];
      w2as[t] = s;
    } else if (t < 128) {
      int c = t - 64;
      float s = 0.f;
      for (int k = 0; k < 100; ++k) s += W2[c * 100 + k] * a2d[k];
      w2ad[c] = s;
    }
  }
}

// ---- CSR build: pass A1 — bucket histogram --------------------------------

__global__ __launch_bounds__(256) void k_hist(const int* __restrict__ ei, int E,
                                              int* __restrict__ bhist) {
  __shared__ int lh[256];
  int tid = threadIdx.x;
  lh[tid] = 0;
  __syncthreads();
  int base = blockIdx.x * 2048;
#pragma unroll
  for (int j = 0; j < 8; ++j) {
    int e = base + j * 256 + tid;
    if (e < E) atomicAdd(&lh[ei[E + e] >> BSH], 1);
  }
  __syncthreads();
  if (lh[tid]) atomicAdd(&bhist[tid], lh[tid]);
}

// ---- pass A2 — scan bucket counts (single block) --------------------------

__global__ __launch_bounds__(256) void k_bscan(const int* __restrict__ bhist,
                                               int* __restrict__ bbase, int* __restrict__ bcur,
                                               int* __restrict__ offs, int K, int E, int N) {
  __shared__ int s[256];
  int tid = threadIdx.x;
  int v = (tid < K) ? bhist[tid] : 0;
  s[tid] = v;
  __syncthreads();
  for (int off = 1; off < 256; off <<= 1) {
    int t = (tid >= off) ? s[tid - off] : 0;
    __syncthreads();
    s[tid] += t;
    __syncthreads();
  }
  int excl = s[tid] - v;
  if (tid < K) { bbase[tid] = excl; bcur[tid] = excl; }
  if (tid == 255) bbase[K] = s[255];    // = E
  if (tid == 0) offs[N] = E + N;
}

// ---- pass A3 — bin edges into buckets, packed src | (dst_local<<17) -------

__global__ __launch_bounds__(256) void k_bin(const int* __restrict__ ei, int E,
                                             int* __restrict__ bcur,
                                             unsigned int* __restrict__ binned) {
  __shared__ int lh[256];
  __shared__ int lbase[256];
  int tid = threadIdx.x;
  lh[tid] = 0;
  __syncthreads();
  int base = blockIdx.x * 2048;
  int bj[8], rk[8];
  unsigned int pk[8];
#pragma unroll
  for (int j = 0; j < 8; ++j) {
    int e = base + j * 256 + tid;
    bj[j] = -1;
    if (e < E) {
      unsigned int sj = (unsigned int)ei[e];
      int d = ei[E + e];
      bj[j] = d >> BSH;
      pk[j] = sj | ((unsigned int)(d & (BNN - 1)) << 17);
      rk[j] = atomicAdd(&lh[bj[j]], 1);
    }
  }
  __syncthreads();
  if (lh[tid]) lbase[tid] = atomicAdd(&bcur[tid], lh[tid]);
  __syncthreads();
#pragma unroll
  for (int j = 0; j < 8; ++j)
    if (bj[j] >= 0) binned[lbase[bj[j]] + rk[j]] = pk[j];
}

// ---- pass B — per-bucket CSR fill (one block per bucket) ------------------

__global__ __launch_bounds__(256) void k_bucket(const unsigned int* __restrict__ binned,
                                                const int* __restrict__ bbase,
                                                int* __restrict__ offs, int* __restrict__ csr,
                                                int N) {
  __shared__ int hist[BNN], loffS[BNN], cur[BNN];
  __shared__ int s[256];
  int tid = threadIdx.x;
  int b = blockIdx.x;
  int node0 = b << BSH;
  int sl = min(BNN, N - node0);
  int e0 = bbase[b], e1 = bbase[b + 1];
  int cbase = e0 + min(node0, N);          // csr base incl. upstream self-loops
  hist[tid] = 0; hist[tid + 256] = 0;
  __syncthreads();
  for (int e = e0 + tid; e < e1; e += 256) atomicAdd(&hist[binned[e] >> 17], 1);
  __syncthreads();
  int a0 = hist[2 * tid], a1 = hist[2 * tid + 1];
  s[tid] = a0 + a1;
  __syncthreads();
  for (int off = 1; off < 256; off <<= 1) {
    int t = (tid >= off) ? s[tid - off] : 0;
    __syncthreads();
    s[tid] += t;
    __syncthreads();
  }
  int excl = s[tid] - (a0 + a1);
  loffS[2 * tid]     = excl + 2 * tid;
  loffS[2 * tid + 1] = excl + a0 + 2 * tid + 1;
  __syncthreads();
  cur[2 * tid] = loffS[2 * tid];
  cur[2 * tid + 1] = loffS[2 * tid + 1];
  if (2 * tid < sl)     offs[node0 + 2 * tid]     = cbase + loffS[2 * tid];
  if (2 * tid + 1 < sl) offs[node0 + 2 * tid + 1] = cbase + loffS[2 * tid + 1];
  __syncthreads();
  for (int e = e0 + tid; e < e1; e += 256) {
    unsigned int u = binned[e];
    int p = atomicAdd(&cur[u >> 17], 1);
    csr[cbase + p] = (int)(u & 0x1FFFFu);
  }
  for (int i = tid; i < sl; i += 256) {
    int p = atomicAdd(&cur[i], 1);
    csr[cbase + p] = node0 + i;            // self loop
  }
}

// ---- Layer 1 GEMM via MFMA: 32-row tile, B hoisted to registers -----------
// Epilogue writes INTERLEAVED asd1[row][16]: [0..7]=alpha_src, [8..15]=alpha_dst
// so agg1's per-edge alpha gather touches ONE 64B sector.

__global__ __launch_bounds__(256) void k_gemm1(const float* __restrict__ x,
                                               const unsigned short* __restrict__ w1t,
                                               const float* __restrict__ av_s, const float* __restrict__ av_d,
                                               unsigned short* __restrict__ h1b,
                                               float* __restrict__ asd1, int N) {
  __shared__ unsigned short xs[32 * 268];
  int tid = threadIdx.x;
  int row0 = blockIdx.x * 32;
  int w = tid >> 6, lane = tid & 63;
  int wr = w & 1, wc = w >> 1;
  int r16 = lane & 15, kg4 = lane >> 4;
  // hoist all 16 B-fragments into registers (independent loads, issued now)
  const unsigned short* pw = &w1t[(32 * wc + r16) * 256 + kg4 * 8];
  short8v breg[8][2];
#pragma unroll
  for (int ks = 0; ks < 8; ++ks) {
#pragma unroll
    for (int f = 0; f < 2; ++f) {
      union { short8v s; uint4 u; } bv;
      bv.u = *(const uint4*)(pw + f * 16 * 256 + ks * 32);
      breg[ks][f] = bv.s;
    }
  }
  // stage x tile fp32->bf16 into LDS (coalesced 1KB runs per row)
#pragma unroll
  for (int it = 0; it < 4; ++it) {
    int slot = tid + it * 256;              // 0..1023
    int row = slot >> 5, kg = slot & 31;    // k-base = kg*8
    int grow = row0 + row;
    uint4 pk = make_uint4(0u, 0u, 0u, 0u);
    if (grow < N) {
      const float* px = &x[(size_t)grow * 256 + kg * 8];
      float4 v0 = *(const float4*)px;
      float4 v1 = *(const float4*)(px + 4);
      pk.x = f2b(v0.x) | ((unsigned)f2b(v0.y) << 16);
      pk.y = f2b(v0.z) | ((unsigned)f2b(v0.w) << 16);
      pk.z = f2b(v1.x) | ((unsigned)f2b(v1.y) << 16);
      pk.w = f2b(v1.z) | ((unsigned)f2b(v1.w) << 16);
    }
    *(uint4*)&xs[row * 268 + kg * 8] = pk;
  }
  __syncthreads();
  f32x4 acc[2];
  acc[0] = (f32x4){0.f, 0.f, 0.f, 0.f};
  acc[1] = (f32x4){0.f, 0.f, 0.f, 0.f};
  const unsigned short* xrow = &xs[(16 * wr + r16) * 268 + kg4 * 8];
#pragma unroll
  for (int ks = 0; ks < 8; ++ks) {
    short8v a = *(const short8v*)(xrow + ks * 32);
    acc[0] = __builtin_amdgcn_mfma_f32_16x16x32_bf16(a, breg[ks][0], acc[0], 0, 0, 0);
    acc[1] = __builtin_amdgcn_mfma_f32_16x16x32_bf16(a, breg[ks][1], acc[1], 0, 0, 0);
  }
  // epilogue: h1 bf16 + per-head alpha reduce. head = 4wc + 2f + (r16>>3)
  float avv[2], bvv[2];
#pragma unroll
  for (int f = 0; f < 2; ++f) {
    avv[f] = av_s[32 * wc + 16 * f + r16];
    bvv[f] = av_d[32 * wc + 16 * f + r16];
  }
  int rbase = row0 + 16 * wr + kg4 * 4;
#pragma unroll
  for (int reg = 0; reg < 4; ++reg) {
    int row = rbase + reg;
    bool ok = row < N;
    if (ok) {
#pragma unroll
      for (int f = 0; f < 2; ++f)
        h1b[(size_t)row * 64 + 32 * wc + 16 * f + r16] = f2b(acc[f][reg]);
    }
    float ts[2], td[2];
#pragma unroll
    for (int f = 0; f < 2; ++f) { ts[f] = acc[f][reg] * avv[f]; td[f] = acc[f][reg] * bvv[f]; }
#pragma unroll
    for (int off = 1; off <= 4; off <<= 1) {
#pragma unroll
      for (int f = 0; f < 2; ++f) {
        ts[f] += __shfl_xor(ts[f], off);
        td[f] += __shfl_xor(td[f], off);
      }
    }
    if (ok && (r16 & 7) == 0) {
      int bsel = r16 >> 3;
#pragma unroll
      for (int f = 0; f < 2; ++f) {
        asd1[row * 16 + 4 * wc + 2 * f + bsel]     = ts[f];
        asd1[row * 16 + 8 + 4 * wc + 2 * f + bsel] = td[f];
      }
    }
  }
}

// ---- Layer 1 aggregate: 8 nodes/wave, 8 lanes/node ------------------------

__global__ __launch_bounds__(256) void k_agg1(const int* __restrict__ csr, const int* __restrict__ offs,
                                              const unsigned short* __restrict__ h1b,
                                              const float* __restrict__ asd1,
                                              const float* __restrict__ b1,
                                              const float* __restrict__ w2as, const float* __restrict__ w2ad,
                                              unsigned short* __restrict__ helu_b,
                                              float* __restrict__ as2, float* __restrict__ ad2, int N) {
  __shared__ float wsm[4][8][8][9];   // [wave][sub][head][edge(pad 9)]
  int tid = threadIdx.x;
  int w = tid >> 6, lane = tid & 63;
  int sub = lane >> 3, q = lane & 7;
  int base = sub << 3;                // first lane of this sub-group
  int node = blockIdx.x * 32 + w * 8 + sub;
  bool valid = node < N;
  int beg = 0, end = 0;
  if (valid) { beg = offs[node]; end = offs[node + 1]; }
  int deg = end - beg;
  int dm = deg;
  dm = max(dm, __shfl_xor(dm, 8));
  dm = max(dm, __shfl_xor(dm, 16));
  dm = max(dm, __shfl_xor(dm, 32));
  float4 advlo = make_float4(0.f, 0.f, 0.f, 0.f), advhi = advlo;
  if (valid) {
    advlo = *(const float4*)&asd1[node * 16 + 8];
    advhi = *(const float4*)&asd1[node * 16 + 12];
  }
  float denom = 0.f;
  float4 acc0 = make_float4(0.f, 0.f, 0.f, 0.f);
  float4 acc1 = make_float4(0.f, 0.f, 0.f, 0.f);
  for (int c0 = 0; c0 < dm; c0 += 8) {
    int cn = min(8, deg - c0);          // may be <= 0 for finished nodes
    int sreg = 0;
    if (q < cn) {
      sreg = csr[beg + c0 + q];
      float4 alo = *(const float4*)&asd1[sreg * 16];
      float4 ahi = *(const float4*)&asd1[sreg * 16 + 4];
      wsm[w][sub][0][q] = __expf(lrelu02(alo.x + advlo.x));
      wsm[w][sub][1][q] = __expf(lrelu02(alo.y + advlo.y));
      wsm[w][sub][2][q] = __expf(lrelu02(alo.z + advlo.z));
      wsm[w][sub][3][q] = __expf(lrelu02(alo.w + advlo.w));
      wsm[w][sub][4][q] = __expf(lrelu02(ahi.x + advhi.x));
      wsm[w][sub][5][q] = __expf(lrelu02(ahi.y + advhi.y));
      wsm[w][sub][6][q] = __expf(lrelu02(ahi.z + advhi.z));
      wsm[w][sub][7][q] = __expf(lrelu02(ahi.w + advhi.w));
    }
    int i = 0;
    for (; i + 2 <= cn; i += 2) {
      int s0 = __shfl(sreg, base + i);
      int s1 = __shfl(sreg, base + i + 1);
      float w0 = wsm[w][sub][q][i];
      float w1 = wsm[w][sub][q][i + 1];
      uint4 p0 = *(const uint4*)&h1b[(unsigned)s0 * 64 + q * 8];
      uint4 p1 = *(const uint4*)&h1b[(unsigned)s1 * 64 + q * 8];
      denom += w0 + w1;
      acc0.x += w0 * lo16(p0.x); acc0.y += w0 * hi16(p0.x);
      acc0.z += w0 * lo16(p0.y); acc0.w += w0 * hi16(p0.y);
      acc1.x += w0 * lo16(p0.z); acc1.y += w0 * hi16(p0.z);
      acc1.z += w0 * lo16(p0.w); acc1.w += w0 * hi16(p0.w);
      acc0.x += w1 * lo16(p1.x); acc0.y += w1 * hi16(p1.x);
      acc0.z += w1 * lo16(p1.y); acc0.w += w1 * hi16(p1.y);
      acc1.x += w1 * lo16(p1.z); acc1.y += w1 * hi16(p1.z);
      acc1.z += w1 * lo16(p1.w); acc1.w += w1 * hi16(p1.w);
    }
    if (i < cn) {
      int s0 = __shfl(sreg, base + i);
      float w0 = wsm[w][sub][q][i];
      uint4 p0 = *(const uint4*)&h1b[(unsigned)s0 * 64 + q * 8];
      denom += w0;
      acc0.x += w0 * lo16(p0.x); acc0.y += w0 * hi16(p0.x);
      acc0.z += w0 * lo16(p0.y); acc0.w += w0 * hi16(p0.y);
      acc1.x += w0 * lo16(p0.z); acc1.y += w0 * hi16(p0.z);
      acc1.z += w0 * lo16(p0.w); acc1.w += w0 * hi16(p0.w);
    }
  }
  // epilogue (denom/acc already complete per lane)
  float rd = 1.f / denom;
  float4 ba = valid ? *(const float4*)&b1[q * 8] : make_float4(0.f, 0.f, 0.f, 0.f);
  float4 bb = valid ? *(const float4*)&b1[q * 8 + 4] : make_float4(0.f, 0.f, 0.f, 0.f);
  float o[8];
  o[0] = acc0.x * rd + ba.x; o[1] = acc0.y * rd + ba.y;
  o[2] = acc0.z * rd + ba.z; o[3] = acc0.w * rd + ba.w;
  o[4] = acc1.x * rd + bb.x; o[5] = acc1.y * rd + bb.y;
  o[6] = acc1.z * rd + bb.z; o[7] = acc1.w * rd + bb.w;
#pragma unroll
  for (int j = 0; j < 8; ++j) o[j] = o[j] > 0.f ? o[j] : __expf(o[j]) - 1.f;  // ELU
  if (valid) {
    uint4 ob;
    ob.x = f2b(o[0]) | ((unsigned)f2b(o[1]) << 16);
    ob.y = f2b(o[2]) | ((unsigned)f2b(o[3]) << 16);
    ob.z = f2b(o[4]) | ((unsigned)f2b(o[5]) << 16);
    ob.w = f2b(o[6]) | ((unsigned)f2b(o[7]) << 16);
    *(uint4*)&helu_b[(size_t)node * 64 + q * 8] = ob;
  }
  // fused layer-2 alpha projection (reduce over the 8 lanes of the node)
  float s2 = 0.f, d2 = 0.f;
  if (valid) {
    float4 wa0 = *(const float4*)&w2as[q * 8];
    float4 wa1 = *(const float4*)&w2as[q * 8 + 4];
    float4 wd0 = *(const float4*)&w2ad[q * 8];
    float4 wd1 = *(const float4*)&w2ad[q * 8 + 4];
    s2 = o[0] * wa0.x + o[1] * wa0.y + o[2] * wa0.z + o[3] * wa0.w
       + o[4] * wa1.x + o[5] * wa1.y + o[6] * wa1.z + o[7] * wa1.w;
    d2 = o[0] * wd0.x + o[1] * wd0.y + o[2] * wd0.z + o[3] * wd0.w
       + o[4] * wd1.x + o[5] * wd1.y + o[6] * wd1.z + o[7] * wd1.w;
  }
#pragma unroll
  for (int off = 1; off <= 4; off <<= 1) {
    s2 += __shfl_xor(s2, off);
    d2 += __shfl_xor(d2, off);
  }
  if (valid && q == 0) { as2[node] = s2; ad2[node] = d2; }
}

// ---- Layer 2 aggregate: 8 nodes/wave, 8 lanes/node, bf16 agg out ----------

__global__ __launch_bounds__(256) void k_agg2(const int* __restrict__ csr, const int* __restrict__ offs,
                                              const unsigned short* __restrict__ helu_b,
                                              const float* __restrict__ as2, const float* __restrict__ ad2,
                                              unsigned short* __restrict__ aggb, int N) {
  int tid = threadIdx.x;
  int lane = tid & 63;
  int sub = lane >> 3, q = lane & 7;
  int base = sub << 3;
  int node = blockIdx.x * 32 + (tid >> 6) * 8 + sub;
  bool valid = node < N;
  int beg = 0, end = 0;
  if (valid) { beg = offs[node]; end = offs[node + 1]; }
  int deg = end - beg;
  int dm = deg;
  dm = max(dm, __shfl_xor(dm, 8));
  dm = max(dm, __shfl_xor(dm, 16));
  dm = max(dm, __shfl_xor(dm, 32));
  float adv = valid ? ad2[node] : 0.f;
  float denom = 0.f;
  float4 acc0 = make_float4(0.f, 0.f, 0.f, 0.f);
  float4 acc1 = make_float4(0.f, 0.f, 0.f, 0.f);
  for (int c0 = 0; c0 < dm; c0 += 8) {
    int cn = min(8, deg - c0);
    int sreg = 0; float wq = 0.f;
    if (q < cn) {
      sreg = csr[beg + c0 + q];
      wq = __expf(lrelu02(as2[sreg] + adv));
    }
    int i = 0;
    for (; i + 2 <= cn; i += 2) {
      int s0 = __shfl(sreg, base + i);
      int s1 = __shfl(sreg, base + i + 1);
      float w0 = __shfl(wq, base + i);
      float w1 = __shfl(wq, base + i + 1);
      uint4 p0 = *(const uint4*)&helu_b[(unsigned)s0 * 64 + q * 8];
      uint4 p1 = *(const uint4*)&helu_b[(unsigned)s1 * 64 + q * 8];
      denom += w0 + w1;
      acc0.x += w0 * lo16(p0.x); acc0.y += w0 * hi16(p0.x);
      acc0.z += w0 * lo16(p0.y); acc0.w += w0 * hi16(p0.y);
      acc1.x += w0 * lo16(p0.z); acc1.y += w0 * hi16(p0.z);
      acc1.z += w0 * lo16(p0.w); acc1.w += w0 * hi16(p0.w);
      acc0.x += w1 * lo16(p1.x); acc0.y += w1 * hi16(p1.x);
      acc0.z += w1 * lo16(p1.y); acc0.w += w1 * hi16(p1.y);
      acc1.x += w1 * lo16(p1.z); acc1.y += w1 * hi16(p1.z);
      acc1.z += w1 * lo16(p1.w); acc1.w += w1 * hi16(p1.w);
    }
    if (i < cn) {
      int s0 = __shfl(sreg, base + i);
      float w0 = __shfl(wq, base + i);
      uint4 p0 = *(const uint4*)&helu_b[(unsigned)s0 * 64 + q * 8];
      denom += w0;
      acc0.x += w0 * lo16(p0.x); acc0.y += w0 * hi16(p0.x);
      acc0.z += w0 * lo16(p0.y); acc0.w += w0 * hi16(p0.y);
      acc1.x += w0 * lo16(p0.z); acc1.y += w0 * hi16(p0.z);
      acc1.z += w0 * lo16(p0.w); acc1.w += w0 * hi16(p0.w);
    }
  }
  if (valid) {
    float rd = 1.f / denom;
    uint4 ob;
    ob.x = f2b(acc0.x * rd) | ((unsigned)f2b(acc0.y * rd) << 16);
    ob.y = f2b(acc0.z * rd) | ((unsigned)f2b(acc0.w * rd) << 16);
    ob.z = f2b(acc1.x * rd) | ((unsigned)f2b(acc1.y * rd) << 16);
    ob.w = f2b(acc1.z * rd) | ((unsigned)f2b(acc1.w * rd) << 16);
    *(uint4*)&aggb[(size_t)node * 64 + q * 8] = ob;
  }
}

// ---- Final GEMM: out = sigmoid(agg @ W2 + b2)  [N,64]@[64,100], bf16 in ---

__global__ __launch_bounds__(256) void k_gemm2b(const unsigned short* __restrict__ aggb,
                                                const float* __restrict__ W2,
                                                const float* __restrict__ b2, float* __restrict__ out, int N) {
  __shared__ float het[64][44];     // [k][row]
  __shared__ float w2l[64 * 100];   // [k][col]
  int tid = threadIdx.x;
  int row0 = blockIdx.x * 40;
  for (int i = tid; i < 6400; i += 256) w2l[i] = W2[i];
  for (int idx = tid; idx < 640; idx += 256) {
    int r = idx >> 4, kq = idx & 15;
    int grow = row0 + r;
    uint2 v = make_uint2(0u, 0u);
    if (grow < N) v = *(const uint2*)&aggb[(size_t)grow * 64 + kq * 4];
    het[kq * 4 + 0][r] = lo16(v.x); het[kq * 4 + 1][r] = hi16(v.x);
    het[kq * 4 + 2][r] = lo16(v.y); het[kq * 4 + 3][r] = hi16(v.y);
  }
  __syncthreads();
  int rg = tid / 25, cg = tid % 25;
  if (rg >= 10) return;
  float acc[4][4] = {};
#pragma unroll 4
  for (int k = 0; k < 64; ++k) {
    float4 xv = *(const float4*)&het[k][rg * 4];
    float4 wv = *(const float4*)&w2l[k * 100 + cg * 4];
    float xa[4] = {xv.x, xv.y, xv.z, xv.w};
    float wa[4] = {wv.x, wv.y, wv.z, wv.w};
#pragma unroll
    for (int i = 0; i < 4; ++i)
#pragma unroll
      for (int j = 0; j < 4; ++j) acc[i][j] += xa[i] * wa[j];
  }
  float bb[4];
#pragma unroll
  for (int j = 0; j < 4; ++j) bb[j] = b2[cg * 4 + j];
#pragma unroll
  for (int i = 0; i < 4; ++i) {
    int row = row0 + rg * 4 + i;
    if (row < N) {
      float4 o;
      o.x = 1.f / (1.f + __expf(-(acc[i][0] + bb[0])));
      o.y = 1.f / (1.f + __expf(-(acc[i][1] + bb[1])));
      o.z = 1.f / (1.f + __expf(-(acc[i][2] + bb[2])));
      o.w = 1.f / (1.f + __expf(-(acc[i][3] + bb[3])));
      *(float4*)&out[(size_t)row * 100 + cg * 4] = o;
    }
  }
}

// ---------------------------------------------------------------------------

extern "C" void kernel_launch(void* const* d_in, const int* in_sizes, int n_in,
                              void* d_out, int out_size, void* d_ws, size_t ws_size,
                              hipStream_t stream) {
  const float* x    = (const float*)d_in[0];
  const int*   ei   = (const int*)d_in[1];    // harness converts integer inputs to int32
  const float* W1   = (const float*)d_in[2];
  const float* a_s1 = (const float*)d_in[3];
  const float* a_d1 = (const float*)d_in[4];
  const float* b1   = (const float*)d_in[5];
  const float* W2   = (const float*)d_in[6];
  const float* a_s2 = (const float*)d_in[7];
  const float* a_d2 = (const float*)d_in[8];
  const float* b2   = (const float*)d_in[9];
  float* out = (float*)d_out;

  const int N = in_sizes[0] / 256;
  const int E = in_sizes[1] / 2;
  const int K = (N + BNN - 1) >> BSH;       // buckets (<=256 for N<=131072)

  char* w = (char*)d_ws;
  size_t off = 0;
  auto alloc = [&](size_t bytes) -> char* {
    char* p = w + off;
    off = (off + bytes + 255) & ~(size_t)255;
    return p;
  };
  unsigned short* h1b    = (unsigned short*)alloc((size_t)N * 64 * 2);
  unsigned short* helu_b = (unsigned short*)alloc((size_t)N * 64 * 2);
  unsigned short* aggb   = (unsigned short*)alloc((size_t)N * 64 * 2);
  unsigned short* w1t    = (unsigned short*)alloc(64 * 256 * 2);
  float* asd1 = (float*)alloc((size_t)N * 16 * 4);
  float* as2  = (float*)alloc((size_t)N * 4);
  float* ad2  = (float*)alloc((size_t)N * 4);
  float* w2as = (float*)alloc(64 * 4);
  float* w2ad = (float*)alloc(64 * 4);
  int*   offs   = (int*)alloc((size_t)(N + 1) * 4);
  int*   csr    = (int*)alloc((size_t)(E + N) * 4);
  unsigned int* binned = (unsigned int*)alloc((size_t)E * 4);
  int*   bhist  = (int*)alloc((size_t)(K + 1) * 4);
  int*   bbase  = (int*)alloc((size_t)(K + 1) * 4);
  int*   bcur   = (int*)alloc((size_t)K * 4);
  (void)ws_size; (void)n_in; (void)out_size;

  k_init<<<17, 256, 0, stream>>>(W1, w1t, W2, a_s2, a_d2, w2as, w2ad, bhist, K);

  int ebl = (E + 2047) / 2048;
  k_hist<<<ebl, 256, 0, stream>>>(ei, E, bhist);
  k_bscan<<<1, 256, 0, stream>>>(bhist, bbase, bcur, offs, K, E, N);
  k_bin<<<ebl, 256, 0, stream>>>(ei, E, bcur, binned);
  k_bucket<<<K, 256, 0, stream>>>(binned, bbase, offs, csr, N);

  k_gemm1<<<(N + 31) / 32, 256, 0, stream>>>(x, w1t, a_s1, a_d1, h1b, asd1, N);
  k_agg1<<<(N + 31) / 32, 256, 0, stream>>>(csr, offs, h1b, asd1, b1, w2as, w2ad,
                                            helu_b, as2, ad2, N);
  k_agg2<<<(N + 31) / 32, 256, 0, stream>>>(csr, offs, helu_b, as2, ad2, aggb, N);
  k_gemm2b<<<(N + 39) / 40, 256, 0, stream>>>(aggb, W2, b2, out, N);
}

// Round 15
// 223.700 us; speedup vs baseline: 1.0825x; 1.0825x over previous
//
#include <hip/hip_runtime.h>
#include <hip/hip_bf16.h>
#include <cmath>

// ---------------------------------------------------------------------------
// GAT 2-layer forward.
// CSR build via 2-level bucketing, OVERLAPPED with gemm1: the latency-bound
// MFMA GEMM is split in two half-row launches, with k_hist fused into the
// first grid and k_bin fused into the second (gemm1 saturates no pipe ->
// CSR work rides its idle capacity). Aggregates: max-free softmax, 8
// nodes/wave, uint4 bf16 gathers. Layer2 alpha projected through W2 and
// fused into agg1; agg bf16; final fp32 GEMM W2 + sigmoid.
// ---------------------------------------------------------------------------

#define BSH 9                 // 512 nodes per bucket; requires N <= 131072
#define BNN (1 << BSH)

typedef __attribute__((ext_vector_type(8))) short short8v;
typedef __attribute__((ext_vector_type(4))) float f32x4;

__device__ __forceinline__ float lrelu02(float v) { return v > 0.f ? v : 0.2f * v; }

__device__ __forceinline__ unsigned short f2b(float f) {
  union { float f; unsigned int i; } c; c.f = f;
  unsigned int r = c.i + 0x7FFFu + ((c.i >> 16) & 1u);   // RNE
  return (unsigned short)(r >> 16);
}
__device__ __forceinline__ float lo16(unsigned int u) {
  union { float f; unsigned int i; } c; c.i = u << 16; return c.f;
}
__device__ __forceinline__ float hi16(unsigned int u) {
  union { float f; unsigned int i; } c; c.i = u & 0xFFFF0000u; return c.f;
}

// ---- init: W1^T->bf16 (blocks 0-15), W2-proj + bhist zero (block 16) ------

__global__ __launch_bounds__(256) void k_init(const float* __restrict__ W1,
                                              unsigned short* __restrict__ w1t,
                                              const float* __restrict__ W2,
                                              const float* __restrict__ a2s,
                                              const float* __restrict__ a2d,
                                              float* __restrict__ w2as, float* __restrict__ w2ad,
                                              int* __restrict__ bhist, int K) {
  int b = blockIdx.x, t = threadIdx.x;
  if (b < 16) {
    int idx = b * 256 + t;                    // 0..4095
#pragma unroll
    for (int j = 0; j < 4; ++j) {
      int e = idx * 4 + j;                    // flat w1t index = col*256 + k
      int col = e >> 8, k = e & 255;
      w1t[e] = f2b(W1[k * 64 + col]);
    }
  } else {
    if (t <= K) bhist[t] = 0;
    if (t < 64) {
      float s = 0.f;
      for (int k = 0; k < 100; ++k) s += W2[t * 100 + k] * a2s[k];
      w2as[t] = s;
    } else if (t < 128) {
      int c = t - 64;
      float s = 0.f;
      for (int k = 0; k < 100; ++k) s += W2[c * 100 + k] * a2d[k];
      w2ad[c] = s;
    }
  }
}

// ---- shared gemm1 device body (32-row tile, B hoisted to registers) -------

__device__ __forceinline__ void gemm1_body(const float* __restrict__ x,
                                           const unsigned short* __restrict__ w1t,
                                           const float* __restrict__ av_s,
                                           const float* __restrict__ av_d,
                                           unsigned short* __restrict__ h1b,
                                           float* __restrict__ as1, float* __restrict__ ad1,
                                           int N, int row0, unsigned short* xs /*32*268*/) {
  int tid = threadIdx.x;
  int w = tid >> 6, lane = tid & 63;
  int wr = w & 1, wc = w >> 1;
  int r16 = lane & 15, kg4 = lane >> 4;
  const unsigned short* pw = &w1t[(32 * wc + r16) * 256 + kg4 * 8];
  short8v breg[8][2];
#pragma unroll
  for (int ks = 0; ks < 8; ++ks) {
#pragma unroll
    for (int f = 0; f < 2; ++f) {
      union { short8v s; uint4 u; } bv;
      bv.u = *(const uint4*)(pw + f * 16 * 256 + ks * 32);
      breg[ks][f] = bv.s;
    }
  }
#pragma unroll
  for (int it = 0; it < 4; ++it) {
    int slot = tid + it * 256;              // 0..1023
    int row = slot >> 5, kg = slot & 31;    // k-base = kg*8
    int grow = row0 + row;
    uint4 pk = make_uint4(0u, 0u, 0u, 0u);
    if (grow < N) {
      const float* px = &x[(size_t)grow * 256 + kg * 8];
      float4 v0 = *(const float4*)px;
      float4 v1 = *(const float4*)(px + 4);
      pk.x = f2b(v0.x) | ((unsigned)f2b(v0.y) << 16);
      pk.y = f2b(v0.z) | ((unsigned)f2b(v0.w) << 16);
      pk.z = f2b(v1.x) | ((unsigned)f2b(v1.y) << 16);
      pk.w = f2b(v1.z) | ((unsigned)f2b(v1.w) << 16);
    }
    *(uint4*)&xs[row * 268 + kg * 8] = pk;
  }
  __syncthreads();
  f32x4 acc[2];
  acc[0] = (f32x4){0.f, 0.f, 0.f, 0.f};
  acc[1] = (f32x4){0.f, 0.f, 0.f, 0.f};
  const unsigned short* xrow = &xs[(16 * wr + r16) * 268 + kg4 * 8];
#pragma unroll
  for (int ks = 0; ks < 8; ++ks) {
    short8v a = *(const short8v*)(xrow + ks * 32);
    acc[0] = __builtin_amdgcn_mfma_f32_16x16x32_bf16(a, breg[ks][0], acc[0], 0, 0, 0);
    acc[1] = __builtin_amdgcn_mfma_f32_16x16x32_bf16(a, breg[ks][1], acc[1], 0, 0, 0);
  }
  float avv[2], bvv[2];
#pragma unroll
  for (int f = 0; f < 2; ++f) {
    avv[f] = av_s[32 * wc + 16 * f + r16];
    bvv[f] = av_d[32 * wc + 16 * f + r16];
  }
  int rbase = row0 + 16 * wr + kg4 * 4;
#pragma unroll
  for (int reg = 0; reg < 4; ++reg) {
    int row = rbase + reg;
    bool ok = row < N;
    if (ok) {
#pragma unroll
      for (int f = 0; f < 2; ++f)
        h1b[(size_t)row * 64 + 32 * wc + 16 * f + r16] = f2b(acc[f][reg]);
    }
    float ts[2], td[2];
#pragma unroll
    for (int f = 0; f < 2; ++f) { ts[f] = acc[f][reg] * avv[f]; td[f] = acc[f][reg] * bvv[f]; }
#pragma unroll
    for (int off = 1; off <= 4; off <<= 1) {
#pragma unroll
      for (int f = 0; f < 2; ++f) {
        ts[f] += __shfl_xor(ts[f], off);
        td[f] += __shfl_xor(td[f], off);
      }
    }
    if (ok && (r16 & 7) == 0) {
      int bsel = r16 >> 3;
#pragma unroll
      for (int f = 0; f < 2; ++f) {
        as1[row * 8 + 4 * wc + 2 * f + bsel] = ts[f];
        ad1[row * 8 + 4 * wc + 2 * f + bsel] = td[f];
      }
    }
  }
}

// ---- fused: gemm1 half A  ||  bucket histogram ----------------------------

__global__ __launch_bounds__(256) void k_g1h(const float* __restrict__ x,
                                             const unsigned short* __restrict__ w1t,
                                             const float* __restrict__ av_s, const float* __restrict__ av_d,
                                             unsigned short* __restrict__ h1b,
                                             float* __restrict__ as1, float* __restrict__ ad1,
                                             int N, int GA,
                                             const int* __restrict__ ei, int E,
                                             int* __restrict__ bhist) {
  __shared__ unsigned short xs[32 * 268];
  if ((int)blockIdx.x < GA) {
    gemm1_body(x, w1t, av_s, av_d, h1b, as1, ad1, N, blockIdx.x * 32, xs);
    return;
  }
  // histogram part
  int* lh = (int*)xs;
  int tid = threadIdx.x;
  lh[tid] = 0;
  __syncthreads();
  int base = (blockIdx.x - GA) * 2048;
#pragma unroll
  for (int j = 0; j < 8; ++j) {
    int e = base + j * 256 + tid;
    if (e < E) atomicAdd(&lh[ei[E + e] >> BSH], 1);
  }
  __syncthreads();
  if (lh[tid]) atomicAdd(&bhist[tid], lh[tid]);
}

// ---- pass A2 — scan bucket counts (single block) --------------------------

__global__ __launch_bounds__(256) void k_bscan(const int* __restrict__ bhist,
                                               int* __restrict__ bbase, int* __restrict__ bcur,
                                               int* __restrict__ offs, int K, int E, int N) {
  __shared__ int s[256];
  int tid = threadIdx.x;
  int v = (tid < K) ? bhist[tid] : 0;
  s[tid] = v;
  __syncthreads();
  for (int off = 1; off < 256; off <<= 1) {
    int t = (tid >= off) ? s[tid - off] : 0;
    __syncthreads();
    s[tid] += t;
    __syncthreads();
  }
  int excl = s[tid] - v;
  if (tid < K) { bbase[tid] = excl; bcur[tid] = excl; }
  if (tid == 255) bbase[K] = s[255];    // = E
  if (tid == 0) offs[N] = E + N;
}

// ---- fused: gemm1 half B  ||  bin edges (packed src | dl<<17) -------------

__global__ __launch_bounds__(256) void k_g1b(const float* __restrict__ x,
                                             const unsigned short* __restrict__ w1t,
                                             const float* __restrict__ av_s, const float* __restrict__ av_d,
                                             unsigned short* __restrict__ h1b,
                                             float* __restrict__ as1, float* __restrict__ ad1,
                                             int N, int rowbase, int GB,
                                             const int* __restrict__ ei, int E,
                                             int* __restrict__ bcur, unsigned int* __restrict__ binned) {
  __shared__ unsigned short xs[32 * 268];
  if ((int)blockIdx.x < GB) {
    gemm1_body(x, w1t, av_s, av_d, h1b, as1, ad1, N, rowbase + blockIdx.x * 32, xs);
    return;
  }
  int* lh = (int*)xs;
  int* lbase = lh + 256;
  int tid = threadIdx.x;
  lh[tid] = 0;
  __syncthreads();
  int base = (blockIdx.x - GB) * 2048;
  int bj[8], rk[8];
  unsigned int pk[8];
#pragma unroll
  for (int j = 0; j < 8; ++j) {
    int e = base + j * 256 + tid;
    bj[j] = -1;
    if (e < E) {
      unsigned int sj = (unsigned int)ei[e];
      int d = ei[E + e];
      bj[j] = d >> BSH;
      pk[j] = sj | ((unsigned int)(d & (BNN - 1)) << 17);
      rk[j] = atomicAdd(&lh[bj[j]], 1);
    }
  }
  __syncthreads();
  if (lh[tid]) lbase[tid] = atomicAdd(&bcur[tid], lh[tid]);
  __syncthreads();
#pragma unroll
  for (int j = 0; j < 8; ++j)
    if (bj[j] >= 0) binned[lbase[bj[j]] + rk[j]] = pk[j];
}

// ---- pass B — per-bucket CSR fill (one block per bucket) ------------------

__global__ __launch_bounds__(256) void k_bucket(const unsigned int* __restrict__ binned,
                                                const int* __restrict__ bbase,
                                                int* __restrict__ offs, int* __restrict__ csr,
                                                int N) {
  __shared__ int hist[BNN], loffS[BNN], cur[BNN];
  __shared__ int s[256];
  int tid = threadIdx.x;
  int b = blockIdx.x;
  int node0 = b << BSH;
  int sl = min(BNN, N - node0);
  int e0 = bbase[b], e1 = bbase[b + 1];
  int cbase = e0 + min(node0, N);          // csr base incl. upstream self-loops
  hist[tid] = 0; hist[tid + 256] = 0;
  __syncthreads();
  for (int e = e0 + tid; e < e1; e += 256) atomicAdd(&hist[binned[e] >> 17], 1);
  __syncthreads();
  int a0 = hist[2 * tid], a1 = hist[2 * tid + 1];
  s[tid] = a0 + a1;
  __syncthreads();
  for (int off = 1; off < 256; off <<= 1) {
    int t = (tid >= off) ? s[tid - off] : 0;
    __syncthreads();
    s[tid] += t;
    __syncthreads();
  }
  int excl = s[tid] - (a0 + a1);
  loffS[2 * tid]     = excl + 2 * tid;
  loffS[2 * tid + 1] = excl + a0 + 2 * tid + 1;
  __syncthreads();
  cur[2 * tid] = loffS[2 * tid];
  cur[2 * tid + 1] = loffS[2 * tid + 1];
  if (2 * tid < sl)     offs[node0 + 2 * tid]     = cbase + loffS[2 * tid];
  if (2 * tid + 1 < sl) offs[node0 + 2 * tid + 1] = cbase + loffS[2 * tid + 1];
  __syncthreads();
  for (int e = e0 + tid; e < e1; e += 256) {
    unsigned int u = binned[e];
    int p = atomicAdd(&cur[u >> 17], 1);
    csr[cbase + p] = (int)(u & 0x1FFFFu);
  }
  for (int i = tid; i < sl; i += 256) {
    int p = atomicAdd(&cur[i], 1);
    csr[cbase + p] = node0 + i;            // self loop
  }
}

// ---- Layer 1 aggregate: 8 nodes/wave, 8 lanes/node ------------------------

__global__ __launch_bounds__(256) void k_agg1(const int* __restrict__ csr, const int* __restrict__ offs,
                                              const unsigned short* __restrict__ h1b,
                                              const float* __restrict__ as1, const float* __restrict__ ad1,
                                              const float* __restrict__ b1,
                                              const float* __restrict__ w2as, const float* __restrict__ w2ad,
                                              unsigned short* __restrict__ helu_b,
                                              float* __restrict__ as2, float* __restrict__ ad2, int N) {
  __shared__ float wsm[4][8][8][9];   // [wave][sub][head][edge(pad 9)]
  int tid = threadIdx.x;
  int w = tid >> 6, lane = tid & 63;
  int sub = lane >> 3, q = lane & 7;
  int base = sub << 3;                // first lane of this sub-group
  int node = blockIdx.x * 32 + w * 8 + sub;
  bool valid = node < N;
  int beg = 0, end = 0;
  if (valid) { beg = offs[node]; end = offs[node + 1]; }
  int deg = end - beg;
  int dm = deg;
  dm = max(dm, __shfl_xor(dm, 8));
  dm = max(dm, __shfl_xor(dm, 16));
  dm = max(dm, __shfl_xor(dm, 32));
  float4 advlo = make_float4(0.f, 0.f, 0.f, 0.f), advhi = advlo;
  if (valid) {
    advlo = *(const float4*)&ad1[node * 8];
    advhi = *(const float4*)&ad1[node * 8 + 4];
  }
  float denom = 0.f;
  float4 acc0 = make_float4(0.f, 0.f, 0.f, 0.f);
  float4 acc1 = make_float4(0.f, 0.f, 0.f, 0.f);
  for (int c0 = 0; c0 < dm; c0 += 8) {
    int cn = min(8, deg - c0);          // may be <= 0 for finished nodes
    int sreg = 0;
    if (q < cn) {
      sreg = csr[beg + c0 + q];
      float4 alo = *(const float4*)&as1[sreg * 8];
      float4 ahi = *(const float4*)&as1[sreg * 8 + 4];
      wsm[w][sub][0][q] = __expf(lrelu02(alo.x + advlo.x));
      wsm[w][sub][1][q] = __expf(lrelu02(alo.y + advlo.y));
      wsm[w][sub][2][q] = __expf(lrelu02(alo.z + advlo.z));
      wsm[w][sub][3][q] = __expf(lrelu02(alo.w + advlo.w));
      wsm[w][sub][4][q] = __expf(lrelu02(ahi.x + advhi.x));
      wsm[w][sub][5][q] = __expf(lrelu02(ahi.y + advhi.y));
      wsm[w][sub][6][q] = __expf(lrelu02(ahi.z + advhi.z));
      wsm[w][sub][7][q] = __expf(lrelu02(ahi.w + advhi.w));
    }
    int i = 0;
    for (; i + 2 <= cn; i += 2) {
      int s0 = __shfl(sreg, base + i);
      int s1 = __shfl(sreg, base + i + 1);
      float w0 = wsm[w][sub][q][i];
      float w1 = wsm[w][sub][q][i + 1];
      uint4 p0 = *(const uint4*)&h1b[(unsigned)s0 * 64 + q * 8];
      uint4 p1 = *(const uint4*)&h1b[(unsigned)s1 * 64 + q * 8];
      denom += w0 + w1;
      acc0.x += w0 * lo16(p0.x); acc0.y += w0 * hi16(p0.x);
      acc0.z += w0 * lo16(p0.y); acc0.w += w0 * hi16(p0.y);
      acc1.x += w0 * lo16(p0.z); acc1.y += w0 * hi16(p0.z);
      acc1.z += w0 * lo16(p0.w); acc1.w += w0 * hi16(p0.w);
      acc0.x += w1 * lo16(p1.x); acc0.y += w1 * hi16(p1.x);
      acc0.z += w1 * lo16(p1.y); acc0.w += w1 * hi16(p1.y);
      acc1.x += w1 * lo16(p1.z); acc1.y += w1 * hi16(p1.z);
      acc1.z += w1 * lo16(p1.w); acc1.w += w1 * hi16(p1.w);
    }
    if (i < cn) {
      int s0 = __shfl(sreg, base + i);
      float w0 = wsm[w][sub][q][i];
      uint4 p0 = *(const uint4*)&h1b[(unsigned)s0 * 64 + q * 8];
      denom += w0;
      acc0.x += w0 * lo16(p0.x); acc0.y += w0 * hi16(p0.x);
      acc0.z += w0 * lo16(p0.y); acc0.w += w0 * hi16(p0.y);
      acc1.x += w0 * lo16(p0.z); acc1.y += w0 * hi16(p0.z);
      acc1.z += w0 * lo16(p0.w); acc1.w += w0 * hi16(p0.w);
    }
  }
  // epilogue (denom/acc already complete per lane)
  float rd = 1.f / denom;
  float4 ba = valid ? *(const float4*)&b1[q * 8] : make_float4(0.f, 0.f, 0.f, 0.f);
  float4 bb = valid ? *(const float4*)&b1[q * 8 + 4] : make_float4(0.f, 0.f, 0.f, 0.f);
  float o[8];
  o[0] = acc0.x * rd + ba.x; o[1] = acc0.y * rd + ba.y;
  o[2] = acc0.z * rd + ba.z; o[3] = acc0.w * rd + ba.w;
  o[4] = acc1.x * rd + bb.x; o[5] = acc1.y * rd + bb.y;
  o[6] = acc1.z * rd + bb.z; o[7] = acc1.w * rd + bb.w;
#pragma unroll
  for (int j = 0; j < 8; ++j) o[j] = o[j] > 0.f ? o[j] : __expf(o[j]) - 1.f;  // ELU
  if (valid) {
    uint4 ob;
    ob.x = f2b(o[0]) | ((unsigned)f2b(o[1]) << 16);
    ob.y = f2b(o[2]) | ((unsigned)f2b(o[3]) << 16);
    ob.z = f2b(o[4]) | ((unsigned)f2b(o[5]) << 16);
    ob.w = f2b(o[6]) | ((unsigned)f2b(o[7]) << 16);
    *(uint4*)&helu_b[(size_t)node * 64 + q * 8] = ob;
  }
  // fused layer-2 alpha projection (reduce over the 8 lanes of the node)
  float s2 = 0.f, d2 = 0.f;
  if (valid) {
    float4 wa0 = *(const float4*)&w2as[q * 8];
    float4 wa1 = *(const float4*)&w2as[q * 8 + 4];
    float4 wd0 = *(const float4*)&w2ad[q * 8];
    float4 wd1 = *(const float4*)&w2ad[q * 8 + 4];
    s2 = o[0] * wa0.x + o[1] * wa0.y + o[2] * wa0.z + o[3] * wa0.w
       + o[4] * wa1.x + o[5] * wa1.y + o[6] * wa1.z + o[7] * wa1.w;
    d2 = o[0] * wd0.x + o[1] * wd0.y + o[2] * wd0.z + o[3] * wd0.w
       + o[4] * wd1.x + o[5] * wd1.y + o[6] * wd1.z + o[7] * wd1.w;
  }
#pragma unroll
  for (int off = 1; off <= 4; off <<= 1) {
    s2 += __shfl_xor(s2, off);
    d2 += __shfl_xor(d2, off);
  }
  if (valid && q == 0) { as2[node] = s2; ad2[node] = d2; }
}

// ---- Layer 2 aggregate: 8 nodes/wave, 8 lanes/node, bf16 agg out ----------

__global__ __launch_bounds__(256) void k_agg2(const int* __restrict__ csr, const int* __restrict__ offs,
                                              const unsigned short* __restrict__ helu_b,
                                              const float* __restrict__ as2, const float* __restrict__ ad2,
                                              unsigned short* __restrict__ aggb, int N) {
  int tid = threadIdx.x;
  int lane = tid & 63;
  int sub = lane >> 3, q = lane & 7;
  int base = sub << 3;
  int node = blockIdx.x * 32 + (tid >> 6) * 8 + sub;
  bool valid = node < N;
  int beg = 0, end = 0;
  if (valid) { beg = offs[node]; end = offs[node + 1]; }
  int deg = end - beg;
  int dm = deg;
  dm = max(dm, __shfl_xor(dm, 8));
  dm = max(dm, __shfl_xor(dm, 16));
  dm = max(dm, __shfl_xor(dm, 32));
  float adv = valid ? ad2[node] : 0.f;
  float denom = 0.f;
  float4 acc0 = make_float4(0.f, 0.f, 0.f, 0.f);
  float4 acc1 = make_float4(0.f, 0.f, 0.f, 0.f);
  for (int c0 = 0; c0 < dm; c0 += 8) {
    int cn = min(8, deg - c0);
    int sreg = 0; float wq = 0.f;
    if (q < cn) {
      sreg = csr[beg + c0 + q];
      wq = __expf(lrelu02(as2[sreg] + adv));
    }
    int i = 0;
    for (; i + 2 <= cn; i += 2) {
      int s0 = __shfl(sreg, base + i);
      int s1 = __shfl(sreg, base + i + 1);
      float w0 = __shfl(wq, base + i);
      float w1 = __shfl(wq, base + i + 1);
      uint4 p0 = *(const uint4*)&helu_b[(unsigned)s0 * 64 + q * 8];
      uint4 p1 = *(const uint4*)&helu_b[(unsigned)s1 * 64 + q * 8];
      denom += w0 + w1;
      acc0.x += w0 * lo16(p0.x); acc0.y += w0 * hi16(p0.x);
      acc0.z += w0 * lo16(p0.y); acc0.w += w0 * hi16(p0.y);
      acc1.x += w0 * lo16(p0.z); acc1.y += w0 * hi16(p0.z);
      acc1.z += w0 * lo16(p0.w); acc1.w += w0 * hi16(p0.w);
      acc0.x += w1 * lo16(p1.x); acc0.y += w1 * hi16(p1.x);
      acc0.z += w1 * lo16(p1.y); acc0.w += w1 * hi16(p1.y);
      acc1.x += w1 * lo16(p1.z); acc1.y += w1 * hi16(p1.z);
      acc1.z += w1 * lo16(p1.w); acc1.w += w1 * hi16(p1.w);
    }
    if (i < cn) {
      int s0 = __shfl(sreg, base + i);
      float w0 = __shfl(wq, base + i);
      uint4 p0 = *(const uint4*)&helu_b[(unsigned)s0 * 64 + q * 8];
      denom += w0;
      acc0.x += w0 * lo16(p0.x); acc0.y += w0 * hi16(p0.x);
      acc0.z += w0 * lo16(p0.y); acc0.w += w0 * hi16(p0.y);
      acc1.x += w0 * lo16(p0.z); acc1.y += w0 * hi16(p0.z);
      acc1.z += w0 * lo16(p0.w); acc1.w += w0 * hi16(p0.w);
    }
  }
  if (valid) {
    float rd = 1.f / denom;
    uint4 ob;
    ob.x = f2b(acc0.x * rd) | ((unsigned)f2b(acc0.y * rd) << 16);
    ob.y = f2b(acc0.z * rd) | ((unsigned)f2b(acc0.w * rd) << 16);
    ob.z = f2b(acc1.x * rd) | ((unsigned)f2b(acc1.y * rd) << 16);
    ob.w = f2b(acc1.z * rd) | ((unsigned)f2b(acc1.w * rd) << 16);
    *(uint4*)&aggb[(size_t)node * 64 + q * 8] = ob;
  }
}

// ---- Final GEMM: out = sigmoid(agg @ W2 + b2)  [N,64]@[64,100], bf16 in ---

__global__ __launch_bounds__(256) void k_gemm2b(const unsigned short* __restrict__ aggb,
                                                const float* __restrict__ W2,
                                                const float* __restrict__ b2, float* __restrict__ out, int N) {
  __shared__ float het[64][44];     // [k][row]
  __shared__ float w2l[64 * 100];   // [k][col]
  int tid = threadIdx.x;
  int row0 = blockIdx.x * 40;
  for (int i = tid; i < 6400; i += 256) w2l[i] = W2[i];
  for (int idx = tid; idx < 640; idx += 256) {
    int r = idx >> 4, kq = idx & 15;
    int grow = row0 + r;
    uint2 v = make_uint2(0u, 0u);
    if (grow < N) v = *(const uint2*)&aggb[(size_t)grow * 64 + kq * 4];
    het[kq * 4 + 0][r] = lo16(v.x); het[kq * 4 + 1][r] = hi16(v.x);
    het[kq * 4 + 2][r] = lo16(v.y); het[kq * 4 + 3][r] = hi16(v.y);
  }
  __syncthreads();
  int rg = tid / 25, cg = tid % 25;
  if (rg >= 10) return;
  float acc[4][4] = {};
#pragma unroll 4
  for (int k = 0; k < 64; ++k) {
    float4 xv = *(const float4*)&het[k][rg * 4];
    float4 wv = *(const float4*)&w2l[k * 100 + cg * 4];
    float xa[4] = {xv.x, xv.y, xv.z, xv.w};
    float wa[4] = {wv.x, wv.y, wv.z, wv.w};
#pragma unroll
    for (int i = 0; i < 4; ++i)
#pragma unroll
      for (int j = 0; j < 4; ++j) acc[i][j] += xa[i] * wa[j];
  }
  float bb[4];
#pragma unroll
  for (int j = 0; j < 4; ++j) bb[j] = b2[cg * 4 + j];
#pragma unroll
  for (int i = 0; i < 4; ++i) {
    int row = row0 + rg * 4 + i;
    if (row < N) {
      float4 o;
      o.x = 1.f / (1.f + __expf(-(acc[i][0] + bb[0])));
      o.y = 1.f / (1.f + __expf(-(acc[i][1] + bb[1])));
      o.z = 1.f / (1.f + __expf(-(acc[i][2] + bb[2])));
      o.w = 1.f / (1.f + __expf(-(acc[i][3] + bb[3])));
      *(float4*)&out[(size_t)row * 100 + cg * 4] = o;
    }
  }
}

// ---------------------------------------------------------------------------

extern "C" void kernel_launch(void* const* d_in, const int* in_sizes, int n_in,
                              void* d_out, int out_size, void* d_ws, size_t ws_size,
                              hipStream_t stream) {
  const float* x    = (const float*)d_in[0];
  const int*   ei   = (const int*)d_in[1];    // harness converts integer inputs to int32
  const float* W1   = (const float*)d_in[2];
  const float* a_s1 = (const float*)d_in[3];
  const float* a_d1 = (const float*)d_in[4];
  const float* b1   = (const float*)d_in[5];
  const float* W2   = (const float*)d_in[6];
  const float* a_s2 = (const float*)d_in[7];
  const float* a_d2 = (const float*)d_in[8];
  const float* b2   = (const float*)d_in[9];
  float* out = (float*)d_out;

  const int N = in_sizes[0] / 256;
  const int E = in_sizes[1] / 2;
  const int K = (N + BNN - 1) >> BSH;       // buckets (<=256 for N<=131072)

  char* w = (char*)d_ws;
  size_t off = 0;
  auto alloc = [&](size_t bytes) -> char* {
    char* p = w + off;
    off = (off + bytes + 255) & ~(size_t)255;
    return p;
  };
  unsigned short* h1b    = (unsigned short*)alloc((size_t)N * 64 * 2);
  unsigned short* helu_b = (unsigned short*)alloc((size_t)N * 64 * 2);
  unsigned short* aggb   = (unsigned short*)alloc((size_t)N * 64 * 2);
  unsigned short* w1t    = (unsigned short*)alloc(64 * 256 * 2);
  float* as1  = (float*)alloc((size_t)N * 8 * 4);
  float* ad1  = (float*)alloc((size_t)N * 8 * 4);
  float* as2  = (float*)alloc((size_t)N * 4);
  float* ad2  = (float*)alloc((size_t)N * 4);
  float* w2as = (float*)alloc(64 * 4);
  float* w2ad = (float*)alloc(64 * 4);
  int*   offs   = (int*)alloc((size_t)(N + 1) * 4);
  int*   csr    = (int*)alloc((size_t)(E + N) * 4);
  unsigned int* binned = (unsigned int*)alloc((size_t)E * 4);
  int*   bhist  = (int*)alloc((size_t)(K + 1) * 4);
  int*   bbase  = (int*)alloc((size_t)(K + 1) * 4);
  int*   bcur   = (int*)alloc((size_t)K * 4);
  (void)ws_size; (void)n_in; (void)out_size;

  k_init<<<17, 256, 0, stream>>>(W1, w1t, W2, a_s2, a_d2, w2as, w2ad, bhist, K);

  // split gemm1 rows in half; fuse hist into half A, bin into half B
  const int ebl = (E + 2047) / 2048;
  const int totalG = (N + 31) / 32;
  const int GA = (totalG + 1) / 2;
  const int GB = totalG - GA;
  const int rowbase = GA * 32;

  k_g1h<<<GA + ebl, 256, 0, stream>>>(x, w1t, a_s1, a_d1, h1b, as1, ad1, N, GA,
                                      ei, E, bhist);
  k_bscan<<<1, 256, 0, stream>>>(bhist, bbase, bcur, offs, K, E, N);
  k_g1b<<<GB + ebl, 256, 0, stream>>>(x, w1t, a_s1, a_d1, h1b, as1, ad1, N, rowbase, GB,
                                      ei, E, bcur, binned);
  k_bucket<<<K, 256, 0, stream>>>(binned, bbase, offs, csr, N);

  k_agg1<<<(N + 31) / 32, 256, 0, stream>>>(csr, offs, h1b, as1, ad1, b1, w2as, w2ad,
                                            helu_b, as2, ad2, N);
  k_agg2<<<(N + 31) / 32, 256, 0, stream>>>(csr, offs, helu_b, as2, ad2, aggb, N);
  k_gemm2b<<<(N + 39) / 40, 256, 0, stream>>>(aggb, W2, b2, out, N);
}

// Round 16
// 206.297 us; speedup vs baseline: 1.1738x; 1.0844x over previous
//
#include <hip/hip_runtime.h>
#include <hip/hip_bf16.h>
#include <cmath>

// ---------------------------------------------------------------------------
// GAT 2-layer forward.
// CSR build fully overlapped with gemm1:
//   k1 = [gemm1 half A || bin->per-bucket segments (zero-based cursors)]
//   k2 = [gemm1 half B || bucket fill (in-block scan of bucket counts)]
// No hist, no bscan kernels. Aggregates: max-free softmax, 8 nodes/wave,
// uint4 bf16 gathers; layer2 alpha fused into agg1; agg bf16; fp32 GEMM W2.
// ---------------------------------------------------------------------------

#define BSH 9                 // 512 nodes per bucket; requires N <= 131072
#define BNN (1 << BSH)
#define SEG 12288             // per-bucket segment capacity (mean 8192, +45 sigma)

typedef __attribute__((ext_vector_type(8))) short short8v;
typedef __attribute__((ext_vector_type(4))) float f32x4;

__device__ __forceinline__ float lrelu02(float v) { return v > 0.f ? v : 0.2f * v; }

__device__ __forceinline__ unsigned short f2b(float f) {
  union { float f; unsigned int i; } c; c.f = f;
  unsigned int r = c.i + 0x7FFFu + ((c.i >> 16) & 1u);   // RNE
  return (unsigned short)(r >> 16);
}
__device__ __forceinline__ float lo16(unsigned int u) {
  union { float f; unsigned int i; } c; c.i = u << 16; return c.f;
}
__device__ __forceinline__ float hi16(unsigned int u) {
  union { float f; unsigned int i; } c; c.i = u & 0xFFFF0000u; return c.f;
}

// ---- init: W1^T->bf16 (blocks 0-15); W2-proj + bcur0 zero + offs[N] (b16) --

__global__ __launch_bounds__(256) void k_init(const float* __restrict__ W1,
                                              unsigned short* __restrict__ w1t,
                                              const float* __restrict__ W2,
                                              const float* __restrict__ a2s,
                                              const float* __restrict__ a2d,
                                              float* __restrict__ w2as, float* __restrict__ w2ad,
                                              int* __restrict__ bcur0, int K,
                                              int* __restrict__ offs, int N, int E) {
  int b = blockIdx.x, t = threadIdx.x;
  if (b < 16) {
    int idx = b * 256 + t;                    // 0..4095
#pragma unroll
    for (int j = 0; j < 4; ++j) {
      int e = idx * 4 + j;                    // flat w1t index = col*256 + k
      int col = e >> 8, k = e & 255;
      w1t[e] = f2b(W1[k * 64 + col]);
    }
  } else {
    if (t < K) bcur0[t] = 0;
    if (t == 255) offs[N] = E + N;
    if (t < 64) {
      float s = 0.f;
      for (int k = 0; k < 100; ++k) s += W2[t * 100 + k] * a2s[k];
      w2as[t] = s;
    } else if (t < 128) {
      int c = t - 64;
      float s = 0.f;
      for (int k = 0; k < 100; ++k) s += W2[c * 100 + k] * a2d[k];
      w2ad[c] = s;
    }
  }
}

// ---- shared gemm1 device body (32-row tile, B hoisted to registers) -------

__device__ __forceinline__ void gemm1_body(const float* __restrict__ x,
                                           const unsigned short* __restrict__ w1t,
                                           const float* __restrict__ av_s,
                                           const float* __restrict__ av_d,
                                           unsigned short* __restrict__ h1b,
                                           float* __restrict__ as1, float* __restrict__ ad1,
                                           int N, int row0, unsigned short* xs /*32*268*/) {
  int tid = threadIdx.x;
  int w = tid >> 6, lane = tid & 63;
  int wr = w & 1, wc = w >> 1;
  int r16 = lane & 15, kg4 = lane >> 4;
  const unsigned short* pw = &w1t[(32 * wc + r16) * 256 + kg4 * 8];
  short8v breg[8][2];
#pragma unroll
  for (int ks = 0; ks < 8; ++ks) {
#pragma unroll
    for (int f = 0; f < 2; ++f) {
      union { short8v s; uint4 u; } bv;
      bv.u = *(const uint4*)(pw + f * 16 * 256 + ks * 32);
      breg[ks][f] = bv.s;
    }
  }
#pragma unroll
  for (int it = 0; it < 4; ++it) {
    int slot = tid + it * 256;              // 0..1023
    int row = slot >> 5, kg = slot & 31;    // k-base = kg*8
    int grow = row0 + row;
    uint4 pk = make_uint4(0u, 0u, 0u, 0u);
    if (grow < N) {
      const float* px = &x[(size_t)grow * 256 + kg * 8];
      float4 v0 = *(const float4*)px;
      float4 v1 = *(const float4*)(px + 4);
      pk.x = f2b(v0.x) | ((unsigned)f2b(v0.y) << 16);
      pk.y = f2b(v0.z) | ((unsigned)f2b(v0.w) << 16);
      pk.z = f2b(v1.x) | ((unsigned)f2b(v1.y) << 16);
      pk.w = f2b(v1.z) | ((unsigned)f2b(v1.w) << 16);
    }
    *(uint4*)&xs[row * 268 + kg * 8] = pk;
  }
  __syncthreads();
  f32x4 acc[2];
  acc[0] = (f32x4){0.f, 0.f, 0.f, 0.f};
  acc[1] = (f32x4){0.f, 0.f, 0.f, 0.f};
  const unsigned short* xrow = &xs[(16 * wr + r16) * 268 + kg4 * 8];
#pragma unroll
  for (int ks = 0; ks < 8; ++ks) {
    short8v a = *(const short8v*)(xrow + ks * 32);
    acc[0] = __builtin_amdgcn_mfma_f32_16x16x32_bf16(a, breg[ks][0], acc[0], 0, 0, 0);
    acc[1] = __builtin_amdgcn_mfma_f32_16x16x32_bf16(a, breg[ks][1], acc[1], 0, 0, 0);
  }
  float avv[2], bvv[2];
#pragma unroll
  for (int f = 0; f < 2; ++f) {
    avv[f] = av_s[32 * wc + 16 * f + r16];
    bvv[f] = av_d[32 * wc + 16 * f + r16];
  }
  int rbase = row0 + 16 * wr + kg4 * 4;
#pragma unroll
  for (int reg = 0; reg < 4; ++reg) {
    int row = rbase + reg;
    bool ok = row < N;
    if (ok) {
#pragma unroll
      for (int f = 0; f < 2; ++f)
        h1b[(size_t)row * 64 + 32 * wc + 16 * f + r16] = f2b(acc[f][reg]);
    }
    float ts[2], td[2];
#pragma unroll
    for (int f = 0; f < 2; ++f) { ts[f] = acc[f][reg] * avv[f]; td[f] = acc[f][reg] * bvv[f]; }
#pragma unroll
    for (int off = 1; off <= 4; off <<= 1) {
#pragma unroll
      for (int f = 0; f < 2; ++f) {
        ts[f] += __shfl_xor(ts[f], off);
        td[f] += __shfl_xor(td[f], off);
      }
    }
    if (ok && (r16 & 7) == 0) {
      int bsel = r16 >> 3;
#pragma unroll
      for (int f = 0; f < 2; ++f) {
        as1[row * 8 + 4 * wc + 2 * f + bsel] = ts[f];
        ad1[row * 8 + 4 * wc + 2 * f + bsel] = td[f];
      }
    }
  }
}

// ---- k1: gemm1 half A  ||  bin into per-bucket segments -------------------
// bin: zero-based cursor bcur0[b]; binned2[b*SEG + pos] = src | (dl<<17).
// bcur0[b] ends as the bucket's edge count (consumed by k2's in-block scan).

__global__ __launch_bounds__(256) void k_g1bin(const float* __restrict__ x,
                                               const unsigned short* __restrict__ w1t,
                                               const float* __restrict__ av_s, const float* __restrict__ av_d,
                                               unsigned short* __restrict__ h1b,
                                               float* __restrict__ as1, float* __restrict__ ad1,
                                               int N, int GA,
                                               const int* __restrict__ ei, int E,
                                               int* __restrict__ bcur0, unsigned int* __restrict__ binned2) {
  __shared__ unsigned short xs[32 * 268];
  if ((int)blockIdx.x < GA) {
    gemm1_body(x, w1t, av_s, av_d, h1b, as1, ad1, N, blockIdx.x * 32, xs);
    return;
  }
  int* lh = (int*)xs;
  int* lbase = lh + 256;
  int tid = threadIdx.x;
  lh[tid] = 0;
  __syncthreads();
  int base = (blockIdx.x - GA) * 2048;
  int bj[8], rk[8];
  unsigned int pk[8];
#pragma unroll
  for (int j = 0; j < 8; ++j) {
    int e = base + j * 256 + tid;
    bj[j] = -1;
    if (e < E) {
      unsigned int sj = (unsigned int)ei[e];
      int d = ei[E + e];
      bj[j] = d >> BSH;
      pk[j] = sj | ((unsigned int)(d & (BNN - 1)) << 17);
      rk[j] = atomicAdd(&lh[bj[j]], 1);
    }
  }
  __syncthreads();
  if (lh[tid]) lbase[tid] = atomicAdd(&bcur0[tid], lh[tid]);
  __syncthreads();
#pragma unroll
  for (int j = 0; j < 8; ++j)
    if (bj[j] >= 0) binned2[(size_t)bj[j] * SEG + lbase[bj[j]] + rk[j]] = pk[j];
}

// ---- k2: gemm1 half B  ||  per-bucket CSR fill (in-block scan) ------------

__global__ __launch_bounds__(256) void k_g1bkt(const float* __restrict__ x,
                                               const unsigned short* __restrict__ w1t,
                                               const float* __restrict__ av_s, const float* __restrict__ av_d,
                                               unsigned short* __restrict__ h1b,
                                               float* __restrict__ as1, float* __restrict__ ad1,
                                               int N, int rowbase, int GB,
                                               const int* __restrict__ bcur0,
                                               const unsigned int* __restrict__ binned2,
                                               int* __restrict__ offs, int* __restrict__ csr, int K) {
  __shared__ unsigned short xs[32 * 268];
  if ((int)blockIdx.x < GB) {
    gemm1_body(x, w1t, av_s, av_d, h1b, as1, ad1, N, rowbase + blockIdx.x * 32, xs);
    return;
  }
  // bucket part: LDS alias (7.5 KB < 17 KB)
  int* hist  = (int*)xs;            // [512]
  int* loffS = hist + BNN;          // [512]
  int* cur   = loffS + BNN;         // [512]
  int* s     = cur + BNN;           // [256]
  __shared__ int sh_e0, sh_cnt;
  int tid = threadIdx.x;
  int b = blockIdx.x - GB;
  int node0 = b << BSH;
  int sl = min(BNN, N - node0);
  // in-block exclusive scan of bucket counts -> e0 (global edge base), cnt
  int v = (tid < K) ? bcur0[tid] : 0;
  s[tid] = v;
  __syncthreads();
  for (int off = 1; off < 256; off <<= 1) {
    int t = (tid >= off) ? s[tid - off] : 0;
    __syncthreads();
    s[tid] += t;
    __syncthreads();
  }
  if (tid == b) { sh_e0 = s[tid] - v; sh_cnt = v; }
  __syncthreads();
  int e0 = sh_e0, cnt = sh_cnt;
  int cbase = e0 + min(node0, N);          // csr base incl. upstream self-loops
  const unsigned int* seg = &binned2[(size_t)b * SEG];
  hist[tid] = 0; hist[tid + 256] = 0;
  __syncthreads();
  for (int e = tid; e < cnt; e += 256) atomicAdd(&hist[seg[e] >> 17], 1);
  __syncthreads();
  int a0 = hist[2 * tid], a1 = hist[2 * tid + 1];
  s[tid] = a0 + a1;
  __syncthreads();
  for (int off = 1; off < 256; off <<= 1) {
    int t = (tid >= off) ? s[tid - off] : 0;
    __syncthreads();
    s[tid] += t;
    __syncthreads();
  }
  int excl = s[tid] - (a0 + a1);
  loffS[2 * tid]     = excl + 2 * tid;
  loffS[2 * tid + 1] = excl + a0 + 2 * tid + 1;
  __syncthreads();
  cur[2 * tid] = loffS[2 * tid];
  cur[2 * tid + 1] = loffS[2 * tid + 1];
  if (2 * tid < sl)     offs[node0 + 2 * tid]     = cbase + loffS[2 * tid];
  if (2 * tid + 1 < sl) offs[node0 + 2 * tid + 1] = cbase + loffS[2 * tid + 1];
  __syncthreads();
  for (int e = tid; e < cnt; e += 256) {
    unsigned int u = seg[e];
    int p = atomicAdd(&cur[u >> 17], 1);
    csr[cbase + p] = (int)(u & 0x1FFFFu);
  }
  for (int i = tid; i < sl; i += 256) {
    int p = atomicAdd(&cur[i], 1);
    csr[cbase + p] = node0 + i;            // self loop
  }
}

// ---- Layer 1 aggregate: 8 nodes/wave, 8 lanes/node ------------------------

__global__ __launch_bounds__(256) void k_agg1(const int* __restrict__ csr, const int* __restrict__ offs,
                                              const unsigned short* __restrict__ h1b,
                                              const float* __restrict__ as1, const float* __restrict__ ad1,
                                              const float* __restrict__ b1,
                                              const float* __restrict__ w2as, const float* __restrict__ w2ad,
                                              unsigned short* __restrict__ helu_b,
                                              float* __restrict__ as2, float* __restrict__ ad2, int N) {
  __shared__ float wsm[4][8][8][9];   // [wave][sub][head][edge(pad 9)]
  int tid = threadIdx.x;
  int w = tid >> 6, lane = tid & 63;
  int sub = lane >> 3, q = lane & 7;
  int base = sub << 3;                // first lane of this sub-group
  int node = blockIdx.x * 32 + w * 8 + sub;
  bool valid = node < N;
  int beg = 0, end = 0;
  if (valid) { beg = offs[node]; end = offs[node + 1]; }
  int deg = end - beg;
  int dm = deg;
  dm = max(dm, __shfl_xor(dm, 8));
  dm = max(dm, __shfl_xor(dm, 16));
  dm = max(dm, __shfl_xor(dm, 32));
  float4 advlo = make_float4(0.f, 0.f, 0.f, 0.f), advhi = advlo;
  if (valid) {
    advlo = *(const float4*)&ad1[node * 8];
    advhi = *(const float4*)&ad1[node * 8 + 4];
  }
  float denom = 0.f;
  float4 acc0 = make_float4(0.f, 0.f, 0.f, 0.f);
  float4 acc1 = make_float4(0.f, 0.f, 0.f, 0.f);
  for (int c0 = 0; c0 < dm; c0 += 8) {
    int cn = min(8, deg - c0);          // may be <= 0 for finished nodes
    int sreg = 0;
    if (q < cn) {
      sreg = csr[beg + c0 + q];
      float4 alo = *(const float4*)&as1[sreg * 8];
      float4 ahi = *(const float4*)&as1[sreg * 8 + 4];
      wsm[w][sub][0][q] = __expf(lrelu02(alo.x + advlo.x));
      wsm[w][sub][1][q] = __expf(lrelu02(alo.y + advlo.y));
      wsm[w][sub][2][q] = __expf(lrelu02(alo.z + advlo.z));
      wsm[w][sub][3][q] = __expf(lrelu02(alo.w + advlo.w));
      wsm[w][sub][4][q] = __expf(lrelu02(ahi.x + advhi.x));
      wsm[w][sub][5][q] = __expf(lrelu02(ahi.y + advhi.y));
      wsm[w][sub][6][q] = __expf(lrelu02(ahi.z + advhi.z));
      wsm[w][sub][7][q] = __expf(lrelu02(ahi.w + advhi.w));
    }
    int i = 0;
    for (; i + 2 <= cn; i += 2) {
      int s0 = __shfl(sreg, base + i);
      int s1 = __shfl(sreg, base + i + 1);
      float w0 = wsm[w][sub][q][i];
      float w1 = wsm[w][sub][q][i + 1];
      uint4 p0 = *(const uint4*)&h1b[(unsigned)s0 * 64 + q * 8];
      uint4 p1 = *(const uint4*)&h1b[(unsigned)s1 * 64 + q * 8];
      denom += w0 + w1;
      acc0.x += w0 * lo16(p0.x); acc0.y += w0 * hi16(p0.x);
      acc0.z += w0 * lo16(p0.y); acc0.w += w0 * hi16(p0.y);
      acc1.x += w0 * lo16(p0.z); acc1.y += w0 * hi16(p0.z);
      acc1.z += w0 * lo16(p0.w); acc1.w += w0 * hi16(p0.w);
      acc0.x += w1 * lo16(p1.x); acc0.y += w1 * hi16(p1.x);
      acc0.z += w1 * lo16(p1.y); acc0.w += w1 * hi16(p1.y);
      acc1.x += w1 * lo16(p1.z); acc1.y += w1 * hi16(p1.z);
      acc1.z += w1 * lo16(p1.w); acc1.w += w1 * hi16(p1.w);
    }
    if (i < cn) {
      int s0 = __shfl(sreg, base + i);
      float w0 = wsm[w][sub][q][i];
      uint4 p0 = *(const uint4*)&h1b[(unsigned)s0 * 64 + q * 8];
      denom += w0;
      acc0.x += w0 * lo16(p0.x); acc0.y += w0 * hi16(p0.x);
      acc0.z += w0 * lo16(p0.y); acc0.w += w0 * hi16(p0.y);
      acc1.x += w0 * lo16(p0.z); acc1.y += w0 * hi16(p0.z);
      acc1.z += w0 * lo16(p0.w); acc1.w += w0 * hi16(p0.w);
    }
  }
  // epilogue (denom/acc already complete per lane)
  float rd = 1.f / denom;
  float4 ba = valid ? *(const float4*)&b1[q * 8] : make_float4(0.f, 0.f, 0.f, 0.f);
  float4 bb = valid ? *(const float4*)&b1[q * 8 + 4] : make_float4(0.f, 0.f, 0.f, 0.f);
  float o[8];
  o[0] = acc0.x * rd + ba.x; o[1] = acc0.y * rd + ba.y;
  o[2] = acc0.z * rd + ba.z; o[3] = acc0.w * rd + ba.w;
  o[4] = acc1.x * rd + bb.x; o[5] = acc1.y * rd + bb.y;
  o[6] = acc1.z * rd + bb.z; o[7] = acc1.w * rd + bb.w;
#pragma unroll
  for (int j = 0; j < 8; ++j) o[j] = o[j] > 0.f ? o[j] : __expf(o[j]) - 1.f;  // ELU
  if (valid) {
    uint4 ob;
    ob.x = f2b(o[0]) | ((unsigned)f2b(o[1]) << 16);
    ob.y = f2b(o[2]) | ((unsigned)f2b(o[3]) << 16);
    ob.z = f2b(o[4]) | ((unsigned)f2b(o[5]) << 16);
    ob.w = f2b(o[6]) | ((unsigned)f2b(o[7]) << 16);
    *(uint4*)&helu_b[(size_t)node * 64 + q * 8] = ob;
  }
  // fused layer-2 alpha projection (reduce over the 8 lanes of the node)
  float s2 = 0.f, d2 = 0.f;
  if (valid) {
    float4 wa0 = *(const float4*)&w2as[q * 8];
    float4 wa1 = *(const float4*)&w2as[q * 8 + 4];
    float4 wd0 = *(const float4*)&w2ad[q * 8];
    float4 wd1 = *(const float4*)&w2ad[q * 8 + 4];
    s2 = o[0] * wa0.x + o[1] * wa0.y + o[2] * wa0.z + o[3] * wa0.w
       + o[4] * wa1.x + o[5] * wa1.y + o[6] * wa1.z + o[7] * wa1.w;
    d2 = o[0] * wd0.x + o[1] * wd0.y + o[2] * wd0.z + o[3] * wd0.w
       + o[4] * wd1.x + o[5] * wd1.y + o[6] * wd1.z + o[7] * wd1.w;
  }
#pragma unroll
  for (int off = 1; off <= 4; off <<= 1) {
    s2 += __shfl_xor(s2, off);
    d2 += __shfl_xor(d2, off);
  }
  if (valid && q == 0) { as2[node] = s2; ad2[node] = d2; }
}

// ---- Layer 2 aggregate: 8 nodes/wave, 8 lanes/node, bf16 agg out ----------

__global__ __launch_bounds__(256) void k_agg2(const int* __restrict__ csr, const int* __restrict__ offs,
                                              const unsigned short* __restrict__ helu_b,
                                              const float* __restrict__ as2, const float* __restrict__ ad2,
                                              unsigned short* __restrict__ aggb, int N) {
  int tid = threadIdx.x;
  int lane = tid & 63;
  int sub = lane >> 3, q = lane & 7;
  int base = sub << 3;
  int node = blockIdx.x * 32 + (tid >> 6) * 8 + sub;
  bool valid = node < N;
  int beg = 0, end = 0;
  if (valid) { beg = offs[node]; end = offs[node + 1]; }
  int deg = end - beg;
  int dm = deg;
  dm = max(dm, __shfl_xor(dm, 8));
  dm = max(dm, __shfl_xor(dm, 16));
  dm = max(dm, __shfl_xor(dm, 32));
  float adv = valid ? ad2[node] : 0.f;
  float denom = 0.f;
  float4 acc0 = make_float4(0.f, 0.f, 0.f, 0.f);
  float4 acc1 = make_float4(0.f, 0.f, 0.f, 0.f);
  for (int c0 = 0; c0 < dm; c0 += 8) {
    int cn = min(8, deg - c0);
    int sreg = 0; float wq = 0.f;
    if (q < cn) {
      sreg = csr[beg + c0 + q];
      wq = __expf(lrelu02(as2[sreg] + adv));
    }
    int i = 0;
    for (; i + 2 <= cn; i += 2) {
      int s0 = __shfl(sreg, base + i);
      int s1 = __shfl(sreg, base + i + 1);
      float w0 = __shfl(wq, base + i);
      float w1 = __shfl(wq, base + i + 1);
      uint4 p0 = *(const uint4*)&helu_b[(unsigned)s0 * 64 + q * 8];
      uint4 p1 = *(const uint4*)&helu_b[(unsigned)s1 * 64 + q * 8];
      denom += w0 + w1;
      acc0.x += w0 * lo16(p0.x); acc0.y += w0 * hi16(p0.x);
      acc0.z += w0 * lo16(p0.y); acc0.w += w0 * hi16(p0.y);
      acc1.x += w0 * lo16(p0.z); acc1.y += w0 * hi16(p0.z);
      acc1.z += w0 * lo16(p0.w); acc1.w += w0 * hi16(p0.w);
      acc0.x += w1 * lo16(p1.x); acc0.y += w1 * hi16(p1.x);
      acc0.z += w1 * lo16(p1.y); acc0.w += w1 * hi16(p1.y);
      acc1.x += w1 * lo16(p1.z); acc1.y += w1 * hi16(p1.z);
      acc1.z += w1 * lo16(p1.w); acc1.w += w1 * hi16(p1.w);
    }
    if (i < cn) {
      int s0 = __shfl(sreg, base + i);
      float w0 = __shfl(wq, base + i);
      uint4 p0 = *(const uint4*)&helu_b[(unsigned)s0 * 64 + q * 8];
      denom += w0;
      acc0.x += w0 * lo16(p0.x); acc0.y += w0 * hi16(p0.x);
      acc0.z += w0 * lo16(p0.y); acc0.w += w0 * hi16(p0.y);
      acc1.x += w0 * lo16(p0.z); acc1.y += w0 * hi16(p0.z);
      acc1.z += w0 * lo16(p0.w); acc1.w += w0 * hi16(p0.w);
    }
  }
  if (valid) {
    float rd = 1.f / denom;
    uint4 ob;
    ob.x = f2b(acc0.x * rd) | ((unsigned)f2b(acc0.y * rd) << 16);
    ob.y = f2b(acc0.z * rd) | ((unsigned)f2b(acc0.w * rd) << 16);
    ob.z = f2b(acc1.x * rd) | ((unsigned)f2b(acc1.y * rd) << 16);
    ob.w = f2b(acc1.z * rd) | ((unsigned)f2b(acc1.w * rd) << 16);
    *(uint4*)&aggb[(size_t)node * 64 + q * 8] = ob;
  }
}

// ---- Final GEMM: out = sigmoid(agg @ W2 + b2)  [N,64]@[64,100], bf16 in ---

__global__ __launch_bounds__(256) void k_gemm2b(const unsigned short* __restrict__ aggb,
                                                const float* __restrict__ W2,
                                                const float* __restrict__ b2, float* __restrict__ out, int N) {
  __shared__ float het[64][44];     // [k][row]
  __shared__ float w2l[64 * 100];   // [k][col]
  int tid = threadIdx.x;
  int row0 = blockIdx.x * 40;
  for (int i = tid; i < 6400; i += 256) w2l[i] = W2[i];
  for (int idx = tid; idx < 640; idx += 256) {
    int r = idx >> 4, kq = idx & 15;
    int grow = row0 + r;
    uint2 v = make_uint2(0u, 0u);
    if (grow < N) v = *(const uint2*)&aggb[(size_t)grow * 64 + kq * 4];
    het[kq * 4 + 0][r] = lo16(v.x); het[kq * 4 + 1][r] = hi16(v.x);
    het[kq * 4 + 2][r] = lo16(v.y); het[kq * 4 + 3][r] = hi16(v.y);
  }
  __syncthreads();
  int rg = tid / 25, cg = tid % 25;
  if (rg >= 10) return;
  float acc[4][4] = {};
#pragma unroll 4
  for (int k = 0; k < 64; ++k) {
    float4 xv = *(const float4*)&het[k][rg * 4];
    float4 wv = *(const float4*)&w2l[k * 100 + cg * 4];
    float xa[4] = {xv.x, xv.y, xv.z, xv.w};
    float wa[4] = {wv.x, wv.y, wv.z, wv.w};
#pragma unroll
    for (int i = 0; i < 4; ++i)
#pragma unroll
      for (int j = 0; j < 4; ++j) acc[i][j] += xa[i] * wa[j];
  }
  float bb[4];
#pragma unroll
  for (int j = 0; j < 4; ++j) bb[j] = b2[cg * 4 + j];
#pragma unroll
  for (int i = 0; i < 4; ++i) {
    int row = row0 + rg * 4 + i;
    if (row < N) {
      float4 o;
      o.x = 1.f / (1.f + __expf(-(acc[i][0] + bb[0])));
      o.y = 1.f / (1.f + __expf(-(acc[i][1] + bb[1])));
      o.z = 1.f / (1.f + __expf(-(acc[i][2] + bb[2])));
      o.w = 1.f / (1.f + __expf(-(acc[i][3] + bb[3])));
      *(float4*)&out[(size_t)row * 100 + cg * 4] = o;
    }
  }
}

// ---------------------------------------------------------------------------

extern "C" void kernel_launch(void* const* d_in, const int* in_sizes, int n_in,
                              void* d_out, int out_size, void* d_ws, size_t ws_size,
                              hipStream_t stream) {
  const float* x    = (const float*)d_in[0];
  const int*   ei   = (const int*)d_in[1];    // harness converts integer inputs to int32
  const float* W1   = (const float*)d_in[2];
  const float* a_s1 = (const float*)d_in[3];
  const float* a_d1 = (const float*)d_in[4];
  const float* b1   = (const float*)d_in[5];
  const float* W2   = (const float*)d_in[6];
  const float* a_s2 = (const float*)d_in[7];
  const float* a_d2 = (const float*)d_in[8];
  const float* b2   = (const float*)d_in[9];
  float* out = (float*)d_out;

  const int N = in_sizes[0] / 256;
  const int E = in_sizes[1] / 2;
  const int K = (N + BNN - 1) >> BSH;       // buckets (<=256 for N<=131072)

  char* w = (char*)d_ws;
  size_t off = 0;
  auto alloc = [&](size_t bytes) -> char* {
    char* p = w + off;
    off = (off + bytes + 255) & ~(size_t)255;
    return p;
  };
  unsigned short* h1b    = (unsigned short*)alloc((size_t)N * 64 * 2);
  unsigned short* helu_b = (unsigned short*)alloc((size_t)N * 64 * 2);
  unsigned short* aggb   = (unsigned short*)alloc((size_t)N * 64 * 2);
  unsigned short* w1t    = (unsigned short*)alloc(64 * 256 * 2);
  float* as1  = (float*)alloc((size_t)N * 8 * 4);
  float* ad1  = (float*)alloc((size_t)N * 8 * 4);
  float* as2  = (float*)alloc((size_t)N * 4);
  float* ad2  = (float*)alloc((size_t)N * 4);
  float* w2as = (float*)alloc(64 * 4);
  float* w2ad = (float*)alloc(64 * 4);
  int*   offs   = (int*)alloc((size_t)(N + 1) * 4);
  int*   csr    = (int*)alloc((size_t)(E + N) * 4);
  unsigned int* binned2 = (unsigned int*)alloc((size_t)K * SEG * 4);
  int*   bcur0  = (int*)alloc((size_t)K * 4);
  (void)ws_size; (void)n_in; (void)out_size;

  k_init<<<17, 256, 0, stream>>>(W1, w1t, W2, a_s2, a_d2, w2as, w2ad, bcur0, K, offs, N, E);

  const int ebl = (E + 2047) / 2048;
  const int totalG = (N + 31) / 32;
  const int GA = (totalG + 1) / 2;
  const int GB = totalG - GA;
  const int rowbase = GA * 32;

  k_g1bin<<<GA + ebl, 256, 0, stream>>>(x, w1t, a_s1, a_d1, h1b, as1, ad1, N, GA,
                                        ei, E, bcur0, binned2);
  k_g1bkt<<<GB + K, 256, 0, stream>>>(x, w1t, a_s1, a_d1, h1b, as1, ad1, N, rowbase, GB,
                                      bcur0, binned2, offs, csr, K);

  k_agg1<<<(N + 31) / 32, 256, 0, stream>>>(csr, offs, h1b, as1, ad1, b1, w2as, w2ad,
                                            helu_b, as2, ad2, N);
  k_agg2<<<(N + 31) / 32, 256, 0, stream>>>(csr, offs, helu_b, as2, ad2, aggb, N);
  k_gemm2b<<<(N + 39) / 40, 256, 0, stream>>>(aggb, W2, b2, out, N);
}

// Round 17
// 199.664 us; speedup vs baseline: 1.2128x; 1.0332x over previous
//
#include <hip/hip_runtime.h>
#include <hip/hip_bf16.h>
#include <cmath>

// ---------------------------------------------------------------------------
// GAT 2-layer forward.
// CSR build fully overlapped with gemm1 (k1=[gemm1A||bin], k2=[gemm1B||bucket]).
// agg1: max-free softmax, 8 nodes/wave, uint4 bf16 gathers, layer2-alpha fused.
// agg2g: aggregation + IN-BLOCK final GEMM (M=32,N=112,K=64 MFMA vs bf16 w2t)
// + bias + sigmoid -> writes `out` directly; no aggb round-trip, no gemm2b.
// ---------------------------------------------------------------------------

#define BSH 9                 // 512 nodes per bucket; requires N <= 131072
#define BNN (1 << BSH)
#define SEG 12288             // per-bucket segment capacity (mean 8192, +45 sigma)

typedef __attribute__((ext_vector_type(8))) short short8v;
typedef __attribute__((ext_vector_type(4))) float f32x4;

__device__ __forceinline__ float lrelu02(float v) { return v > 0.f ? v : 0.2f * v; }

__device__ __forceinline__ unsigned short f2b(float f) {
  union { float f; unsigned int i; } c; c.f = f;
  unsigned int r = c.i + 0x7FFFu + ((c.i >> 16) & 1u);   // RNE
  return (unsigned short)(r >> 16);
}
__device__ __forceinline__ float lo16(unsigned int u) {
  union { float f; unsigned int i; } c; c.i = u << 16; return c.f;
}
__device__ __forceinline__ float hi16(unsigned int u) {
  union { float f; unsigned int i; } c; c.i = u & 0xFFFF0000u; return c.f;
}

// ---- init: W1^T->bf16 (blocks 0-15); W2-proj + w2t bf16 + bcur0 (block 16) --

__global__ __launch_bounds__(256) void k_init(const float* __restrict__ W1,
                                              unsigned short* __restrict__ w1t,
                                              const float* __restrict__ W2,
                                              const float* __restrict__ a2s,
                                              const float* __restrict__ a2d,
                                              float* __restrict__ w2as, float* __restrict__ w2ad,
                                              unsigned short* __restrict__ w2t,
                                              int* __restrict__ bcur0, int K,
                                              int* __restrict__ offs, int N, int E) {
  int b = blockIdx.x, t = threadIdx.x;
  if (b < 16) {
    int idx = b * 256 + t;                    // 0..4095
#pragma unroll
    for (int j = 0; j < 4; ++j) {
      int e = idx * 4 + j;                    // flat w1t index = col*256 + k
      int col = e >> 8, k = e & 255;
      w1t[e] = f2b(W1[k * 64 + col]);
    }
  } else {
    if (t < K) bcur0[t] = 0;
    if (t == 255) offs[N] = E + N;
    if (t < 64) {
      float s = 0.f;
      for (int k = 0; k < 100; ++k) s += W2[t * 100 + k] * a2s[k];
      w2as[t] = s;
    } else if (t < 128) {
      int c = t - 64;
      float s = 0.f;
      for (int k = 0; k < 100; ++k) s += W2[c * 100 + k] * a2d[k];
      w2ad[c] = s;
    }
    // w2t[c][k] = bf16(W2[k][c]), c<112 (pad cols 100..111 with 0)
    for (int i = t; i < 112 * 64; i += 256) {
      int c = i >> 6, k = i & 63;
      w2t[i] = f2b(c < 100 ? W2[k * 100 + c] : 0.f);
    }
  }
}

// ---- shared gemm1 device body (32-row tile, B hoisted to registers) -------

__device__ __forceinline__ void gemm1_body(const float* __restrict__ x,
                                           const unsigned short* __restrict__ w1t,
                                           const float* __restrict__ av_s,
                                           const float* __restrict__ av_d,
                                           unsigned short* __restrict__ h1b,
                                           float* __restrict__ as1, float* __restrict__ ad1,
                                           int N, int row0, unsigned short* xs /*32*268*/) {
  int tid = threadIdx.x;
  int w = tid >> 6, lane = tid & 63;
  int wr = w & 1, wc = w >> 1;
  int r16 = lane & 15, kg4 = lane >> 4;
  const unsigned short* pw = &w1t[(32 * wc + r16) * 256 + kg4 * 8];
  short8v breg[8][2];
#pragma unroll
  for (int ks = 0; ks < 8; ++ks) {
#pragma unroll
    for (int f = 0; f < 2; ++f) {
      union { short8v s; uint4 u; } bv;
      bv.u = *(const uint4*)(pw + f * 16 * 256 + ks * 32);
      breg[ks][f] = bv.s;
    }
  }
#pragma unroll
  for (int it = 0; it < 4; ++it) {
    int slot = tid + it * 256;              // 0..1023
    int row = slot >> 5, kg = slot & 31;    // k-base = kg*8
    int grow = row0 + row;
    uint4 pk = make_uint4(0u, 0u, 0u, 0u);
    if (grow < N) {
      const float* px = &x[(size_t)grow * 256 + kg * 8];
      float4 v0 = *(const float4*)px;
      float4 v1 = *(const float4*)(px + 4);
      pk.x = f2b(v0.x) | ((unsigned)f2b(v0.y) << 16);
      pk.y = f2b(v0.z) | ((unsigned)f2b(v0.w) << 16);
      pk.z = f2b(v1.x) | ((unsigned)f2b(v1.y) << 16);
      pk.w = f2b(v1.z) | ((unsigned)f2b(v1.w) << 16);
    }
    *(uint4*)&xs[row * 268 + kg * 8] = pk;
  }
  __syncthreads();
  f32x4 acc[2];
  acc[0] = (f32x4){0.f, 0.f, 0.f, 0.f};
  acc[1] = (f32x4){0.f, 0.f, 0.f, 0.f};
  const unsigned short* xrow = &xs[(16 * wr + r16) * 268 + kg4 * 8];
#pragma unroll
  for (int ks = 0; ks < 8; ++ks) {
    short8v a = *(const short8v*)(xrow + ks * 32);
    acc[0] = __builtin_amdgcn_mfma_f32_16x16x32_bf16(a, breg[ks][0], acc[0], 0, 0, 0);
    acc[1] = __builtin_amdgcn_mfma_f32_16x16x32_bf16(a, breg[ks][1], acc[1], 0, 0, 0);
  }
  float avv[2], bvv[2];
#pragma unroll
  for (int f = 0; f < 2; ++f) {
    avv[f] = av_s[32 * wc + 16 * f + r16];
    bvv[f] = av_d[32 * wc + 16 * f + r16];
  }
  int rbase = row0 + 16 * wr + kg4 * 4;
#pragma unroll
  for (int reg = 0; reg < 4; ++reg) {
    int row = rbase + reg;
    bool ok = row < N;
    if (ok) {
#pragma unroll
      for (int f = 0; f < 2; ++f)
        h1b[(size_t)row * 64 + 32 * wc + 16 * f + r16] = f2b(acc[f][reg]);
    }
    float ts[2], td[2];
#pragma unroll
    for (int f = 0; f < 2; ++f) { ts[f] = acc[f][reg] * avv[f]; td[f] = acc[f][reg] * bvv[f]; }
#pragma unroll
    for (int off = 1; off <= 4; off <<= 1) {
#pragma unroll
      for (int f = 0; f < 2; ++f) {
        ts[f] += __shfl_xor(ts[f], off);
        td[f] += __shfl_xor(td[f], off);
      }
    }
    if (ok && (r16 & 7) == 0) {
      int bsel = r16 >> 3;
#pragma unroll
      for (int f = 0; f < 2; ++f) {
        as1[row * 8 + 4 * wc + 2 * f + bsel] = ts[f];
        ad1[row * 8 + 4 * wc + 2 * f + bsel] = td[f];
      }
    }
  }
}

// ---- k1: gemm1 half A  ||  bin into per-bucket segments -------------------

__global__ __launch_bounds__(256) void k_g1bin(const float* __restrict__ x,
                                               const unsigned short* __restrict__ w1t,
                                               const float* __restrict__ av_s, const float* __restrict__ av_d,
                                               unsigned short* __restrict__ h1b,
                                               float* __restrict__ as1, float* __restrict__ ad1,
                                               int N, int GA,
                                               const int* __restrict__ ei, int E,
                                               int* __restrict__ bcur0, unsigned int* __restrict__ binned2) {
  __shared__ unsigned short xs[32 * 268];
  if ((int)blockIdx.x < GA) {
    gemm1_body(x, w1t, av_s, av_d, h1b, as1, ad1, N, blockIdx.x * 32, xs);
    return;
  }
  int* lh = (int*)xs;
  int* lbase = lh + 256;
  int tid = threadIdx.x;
  lh[tid] = 0;
  __syncthreads();
  int base = (blockIdx.x - GA) * 2048;
  int bj[8], rk[8];
  unsigned int pk[8];
#pragma unroll
  for (int j = 0; j < 8; ++j) {
    int e = base + j * 256 + tid;
    bj[j] = -1;
    if (e < E) {
      unsigned int sj = (unsigned int)ei[e];
      int d = ei[E + e];
      bj[j] = d >> BSH;
      pk[j] = sj | ((unsigned int)(d & (BNN - 1)) << 17);
      rk[j] = atomicAdd(&lh[bj[j]], 1);
    }
  }
  __syncthreads();
  if (lh[tid]) lbase[tid] = atomicAdd(&bcur0[tid], lh[tid]);
  __syncthreads();
#pragma unroll
  for (int j = 0; j < 8; ++j)
    if (bj[j] >= 0) binned2[(size_t)bj[j] * SEG + lbase[bj[j]] + rk[j]] = pk[j];
}

// ---- k2: gemm1 half B  ||  per-bucket CSR fill (in-block scan) ------------

__global__ __launch_bounds__(256) void k_g1bkt(const float* __restrict__ x,
                                               const unsigned short* __restrict__ w1t,
                                               const float* __restrict__ av_s, const float* __restrict__ av_d,
                                               unsigned short* __restrict__ h1b,
                                               float* __restrict__ as1, float* __restrict__ ad1,
                                               int N, int rowbase, int GB,
                                               const int* __restrict__ bcur0,
                                               const unsigned int* __restrict__ binned2,
                                               int* __restrict__ offs, int* __restrict__ csr, int K) {
  __shared__ unsigned short xs[32 * 268];
  if ((int)blockIdx.x < GB) {
    gemm1_body(x, w1t, av_s, av_d, h1b, as1, ad1, N, rowbase + blockIdx.x * 32, xs);
    return;
  }
  int* hist  = (int*)xs;            // [512]
  int* loffS = hist + BNN;          // [512]
  int* cur   = loffS + BNN;         // [512]
  int* s     = cur + BNN;           // [256]
  __shared__ int sh_e0, sh_cnt;
  int tid = threadIdx.x;
  int b = blockIdx.x - GB;
  int node0 = b << BSH;
  int sl = min(BNN, N - node0);
  int v = (tid < K) ? bcur0[tid] : 0;
  s[tid] = v;
  __syncthreads();
  for (int off = 1; off < 256; off <<= 1) {
    int t = (tid >= off) ? s[tid - off] : 0;
    __syncthreads();
    s[tid] += t;
    __syncthreads();
  }
  if (tid == b) { sh_e0 = s[tid] - v; sh_cnt = v; }
  __syncthreads();
  int e0 = sh_e0, cnt = sh_cnt;
  int cbase = e0 + min(node0, N);          // csr base incl. upstream self-loops
  const unsigned int* seg = &binned2[(size_t)b * SEG];
  hist[tid] = 0; hist[tid + 256] = 0;
  __syncthreads();
  for (int e = tid; e < cnt; e += 256) atomicAdd(&hist[seg[e] >> 17], 1);
  __syncthreads();
  int a0 = hist[2 * tid], a1 = hist[2 * tid + 1];
  s[tid] = a0 + a1;
  __syncthreads();
  for (int off = 1; off < 256; off <<= 1) {
    int t = (tid >= off) ? s[tid - off] : 0;
    __syncthreads();
    s[tid] += t;
    __syncthreads();
  }
  int excl = s[tid] - (a0 + a1);
  loffS[2 * tid]     = excl + 2 * tid;
  loffS[2 * tid + 1] = excl + a0 + 2 * tid + 1;
  __syncthreads();
  cur[2 * tid] = loffS[2 * tid];
  cur[2 * tid + 1] = loffS[2 * tid + 1];
  if (2 * tid < sl)     offs[node0 + 2 * tid]     = cbase + loffS[2 * tid];
  if (2 * tid + 1 < sl) offs[node0 + 2 * tid + 1] = cbase + loffS[2 * tid + 1];
  __syncthreads();
  for (int e = tid; e < cnt; e += 256) {
    unsigned int u = seg[e];
    int p = atomicAdd(&cur[u >> 17], 1);
    csr[cbase + p] = (int)(u & 0x1FFFFu);
  }
  for (int i = tid; i < sl; i += 256) {
    int p = atomicAdd(&cur[i], 1);
    csr[cbase + p] = node0 + i;            // self loop
  }
}

// ---- Layer 1 aggregate: 8 nodes/wave, 8 lanes/node ------------------------

__global__ __launch_bounds__(256) void k_agg1(const int* __restrict__ csr, const int* __restrict__ offs,
                                              const unsigned short* __restrict__ h1b,
                                              const float* __restrict__ as1, const float* __restrict__ ad1,
                                              const float* __restrict__ b1,
                                              const float* __restrict__ w2as, const float* __restrict__ w2ad,
                                              unsigned short* __restrict__ helu_b,
                                              float* __restrict__ as2, float* __restrict__ ad2, int N) {
  __shared__ float wsm[4][8][8][9];   // [wave][sub][head][edge(pad 9)]
  int tid = threadIdx.x;
  int w = tid >> 6, lane = tid & 63;
  int sub = lane >> 3, q = lane & 7;
  int base = sub << 3;                // first lane of this sub-group
  int node = blockIdx.x * 32 + w * 8 + sub;
  bool valid = node < N;
  int beg = 0, end = 0;
  if (valid) { beg = offs[node]; end = offs[node + 1]; }
  int deg = end - beg;
  int dm = deg;
  dm = max(dm, __shfl_xor(dm, 8));
  dm = max(dm, __shfl_xor(dm, 16));
  dm = max(dm, __shfl_xor(dm, 32));
  float4 advlo = make_float4(0.f, 0.f, 0.f, 0.f), advhi = advlo;
  if (valid) {
    advlo = *(const float4*)&ad1[node * 8];
    advhi = *(const float4*)&ad1[node * 8 + 4];
  }
  float denom = 0.f;
  float4 acc0 = make_float4(0.f, 0.f, 0.f, 0.f);
  float4 acc1 = make_float4(0.f, 0.f, 0.f, 0.f);
  for (int c0 = 0; c0 < dm; c0 += 8) {
    int cn = min(8, deg - c0);          // may be <= 0 for finished nodes
    int sreg = 0;
    if (q < cn) {
      sreg = csr[beg + c0 + q];
      float4 alo = *(const float4*)&as1[sreg * 8];
      float4 ahi = *(const float4*)&as1[sreg * 8 + 4];
      wsm[w][sub][0][q] = __expf(lrelu02(alo.x + advlo.x));
      wsm[w][sub][1][q] = __expf(lrelu02(alo.y + advlo.y));
      wsm[w][sub][2][q] = __expf(lrelu02(alo.z + advlo.z));
      wsm[w][sub][3][q] = __expf(lrelu02(alo.w + advlo.w));
      wsm[w][sub][4][q] = __expf(lrelu02(ahi.x + advhi.x));
      wsm[w][sub][5][q] = __expf(lrelu02(ahi.y + advhi.y));
      wsm[w][sub][6][q] = __expf(lrelu02(ahi.z + advhi.z));
      wsm[w][sub][7][q] = __expf(lrelu02(ahi.w + advhi.w));
    }
    int i = 0;
    for (; i + 2 <= cn; i += 2) {
      int s0 = __shfl(sreg, base + i);
      int s1 = __shfl(sreg, base + i + 1);
      float w0 = wsm[w][sub][q][i];
      float w1 = wsm[w][sub][q][i + 1];
      uint4 p0 = *(const uint4*)&h1b[(unsigned)s0 * 64 + q * 8];
      uint4 p1 = *(const uint4*)&h1b[(unsigned)s1 * 64 + q * 8];
      denom += w0 + w1;
      acc0.x += w0 * lo16(p0.x); acc0.y += w0 * hi16(p0.x);
      acc0.z += w0 * lo16(p0.y); acc0.w += w0 * hi16(p0.y);
      acc1.x += w0 * lo16(p0.z); acc1.y += w0 * hi16(p0.z);
      acc1.z += w0 * lo16(p0.w); acc1.w += w0 * hi16(p0.w);
      acc0.x += w1 * lo16(p1.x); acc0.y += w1 * hi16(p1.x);
      acc0.z += w1 * lo16(p1.y); acc0.w += w1 * hi16(p1.y);
      acc1.x += w1 * lo16(p1.z); acc1.y += w1 * hi16(p1.z);
      acc1.z += w1 * lo16(p1.w); acc1.w += w1 * hi16(p1.w);
    }
    if (i < cn) {
      int s0 = __shfl(sreg, base + i);
      float w0 = wsm[w][sub][q][i];
      uint4 p0 = *(const uint4*)&h1b[(unsigned)s0 * 64 + q * 8];
      denom += w0;
      acc0.x += w0 * lo16(p0.x); acc0.y += w0 * hi16(p0.x);
      acc0.z += w0 * lo16(p0.y); acc0.w += w0 * hi16(p0.y);
      acc1.x += w0 * lo16(p0.z); acc1.y += w0 * hi16(p0.z);
      acc1.z += w0 * lo16(p0.w); acc1.w += w0 * hi16(p0.w);
    }
  }
  // epilogue (denom/acc already complete per lane)
  float rd = 1.f / denom;
  float4 ba = valid ? *(const float4*)&b1[q * 8] : make_float4(0.f, 0.f, 0.f, 0.f);
  float4 bb = valid ? *(const float4*)&b1[q * 8 + 4] : make_float4(0.f, 0.f, 0.f, 0.f);
  float o[8];
  o[0] = acc0.x * rd + ba.x; o[1] = acc0.y * rd + ba.y;
  o[2] = acc0.z * rd + ba.z; o[3] = acc0.w * rd + ba.w;
  o[4] = acc1.x * rd + bb.x; o[5] = acc1.y * rd + bb.y;
  o[6] = acc1.z * rd + bb.z; o[7] = acc1.w * rd + bb.w;
#pragma unroll
  for (int j = 0; j < 8; ++j) o[j] = o[j] > 0.f ? o[j] : __expf(o[j]) - 1.f;  // ELU
  if (valid) {
    uint4 ob;
    ob.x = f2b(o[0]) | ((unsigned)f2b(o[1]) << 16);
    ob.y = f2b(o[2]) | ((unsigned)f2b(o[3]) << 16);
    ob.z = f2b(o[4]) | ((unsigned)f2b(o[5]) << 16);
    ob.w = f2b(o[6]) | ((unsigned)f2b(o[7]) << 16);
    *(uint4*)&helu_b[(size_t)node * 64 + q * 8] = ob;
  }
  // fused layer-2 alpha projection (reduce over the 8 lanes of the node)
  float s2 = 0.f, d2 = 0.f;
  if (valid) {
    float4 wa0 = *(const float4*)&w2as[q * 8];
    float4 wa1 = *(const float4*)&w2as[q * 8 + 4];
    float4 wd0 = *(const float4*)&w2ad[q * 8];
    float4 wd1 = *(const float4*)&w2ad[q * 8 + 4];
    s2 = o[0] * wa0.x + o[1] * wa0.y + o[2] * wa0.z + o[3] * wa0.w
       + o[4] * wa1.x + o[5] * wa1.y + o[6] * wa1.z + o[7] * wa1.w;
    d2 = o[0] * wd0.x + o[1] * wd0.y + o[2] * wd0.z + o[3] * wd0.w
       + o[4] * wd1.x + o[5] * wd1.y + o[6] * wd1.z + o[7] * wd1.w;
  }
#pragma unroll
  for (int off = 1; off <= 4; off <<= 1) {
    s2 += __shfl_xor(s2, off);
    d2 += __shfl_xor(d2, off);
  }
  if (valid && q == 0) { as2[node] = s2; ad2[node] = d2; }
}

// ---- Layer 2 aggregate + fused final GEMM + sigmoid -----------------------
// Phase 1: aggregation (8 nodes/wave, 32 nodes/block) -> bf16 tile in LDS.
// Phase 2: out[32 nodes][100] = sigmoid(tile @ W2 + b2) via 16x16x32 MFMA
// (M=32, Npad=112, K=64; 14 C-tiles split across 4 waves; B from w2t, L1-hot).

__global__ __launch_bounds__(256) void k_agg2g(const int* __restrict__ csr, const int* __restrict__ offs,
                                               const unsigned short* __restrict__ helu_b,
                                               const float* __restrict__ as2, const float* __restrict__ ad2,
                                               const unsigned short* __restrict__ w2t,
                                               const float* __restrict__ b2,
                                               float* __restrict__ out, int N) {
  __shared__ unsigned short aggl[32 * 68];   // [node_in_block][ch], pad 68
  int tid = threadIdx.x;
  int w = tid >> 6, lane = tid & 63;
  int sub = lane >> 3, q = lane & 7;
  int base = sub << 3;
  int nb = w * 8 + sub;
  int node = blockIdx.x * 32 + nb;
  bool valid = node < N;
  int beg = 0, end = 0;
  if (valid) { beg = offs[node]; end = offs[node + 1]; }
  int deg = end - beg;
  int dm = deg;
  dm = max(dm, __shfl_xor(dm, 8));
  dm = max(dm, __shfl_xor(dm, 16));
  dm = max(dm, __shfl_xor(dm, 32));
  float adv = valid ? ad2[node] : 0.f;
  float denom = 0.f;
  float4 acc0 = make_float4(0.f, 0.f, 0.f, 0.f);
  float4 acc1 = make_float4(0.f, 0.f, 0.f, 0.f);
  for (int c0 = 0; c0 < dm; c0 += 8) {
    int cn = min(8, deg - c0);
    int sreg = 0; float wq = 0.f;
    if (q < cn) {
      sreg = csr[beg + c0 + q];
      wq = __expf(lrelu02(as2[sreg] + adv));
    }
    int i = 0;
    for (; i + 2 <= cn; i += 2) {
      int s0 = __shfl(sreg, base + i);
      int s1 = __shfl(sreg, base + i + 1);
      float w0 = __shfl(wq, base + i);
      float w1 = __shfl(wq, base + i + 1);
      uint4 p0 = *(const uint4*)&helu_b[(unsigned)s0 * 64 + q * 8];
      uint4 p1 = *(const uint4*)&helu_b[(unsigned)s1 * 64 + q * 8];
      denom += w0 + w1;
      acc0.x += w0 * lo16(p0.x); acc0.y += w0 * hi16(p0.x);
      acc0.z += w0 * lo16(p0.y); acc0.w += w0 * hi16(p0.y);
      acc1.x += w0 * lo16(p0.z); acc1.y += w0 * hi16(p0.z);
      acc1.z += w0 * lo16(p0.w); acc1.w += w0 * hi16(p0.w);
      acc0.x += w1 * lo16(p1.x); acc0.y += w1 * hi16(p1.x);
      acc0.z += w1 * lo16(p1.y); acc0.w += w1 * hi16(p1.y);
      acc1.x += w1 * lo16(p1.z); acc1.y += w1 * hi16(p1.z);
      acc1.z += w1 * lo16(p1.w); acc1.w += w1 * hi16(p1.w);
    }
    if (i < cn) {
      int s0 = __shfl(sreg, base + i);
      float w0 = __shfl(wq, base + i);
      uint4 p0 = *(const uint4*)&helu_b[(unsigned)s0 * 64 + q * 8];
      denom += w0;
      acc0.x += w0 * lo16(p0.x); acc0.y += w0 * hi16(p0.x);
      acc0.z += w0 * lo16(p0.y); acc0.w += w0 * hi16(p0.y);
      acc1.x += w0 * lo16(p0.z); acc1.y += w0 * hi16(p0.z);
      acc1.z += w0 * lo16(p0.w); acc1.w += w0 * hi16(p0.w);
    }
  }
  // stage bf16 aggregate into LDS (invalid rows may be NaN; never stored)
  float rd = valid ? (1.f / denom) : 0.f;
  uint4 ob;
  ob.x = f2b(acc0.x * rd) | ((unsigned)f2b(acc0.y * rd) << 16);
  ob.y = f2b(acc0.z * rd) | ((unsigned)f2b(acc0.w * rd) << 16);
  ob.z = f2b(acc1.x * rd) | ((unsigned)f2b(acc1.y * rd) << 16);
  ob.w = f2b(acc1.z * rd) | ((unsigned)f2b(acc1.w * rd) << 16);
  *(uint4*)&aggl[nb * 68 + q * 8] = ob;
  __syncthreads();
  // mini-GEMM: C-tile t (m=t&1, n=t>>1); wave w does t = w, w+4, w+8, w+12
  int r16 = lane & 15, kg4 = lane >> 4;
#pragma unroll
  for (int tt = 0; tt < 4; ++tt) {
    int t = w + tt * 4;
    if (t >= 14) break;
    int m = t & 1, n = t >> 1;
    f32x4 cacc = (f32x4){0.f, 0.f, 0.f, 0.f};
#pragma unroll
    for (int ks = 0; ks < 2; ++ks) {
      short8v a = *(const short8v*)&aggl[(16 * m + r16) * 68 + ks * 32 + kg4 * 8];
      short8v b = *(const short8v*)&w2t[(16 * n + r16) * 64 + ks * 32 + kg4 * 8];
      cacc = __builtin_amdgcn_mfma_f32_16x16x32_bf16(a, b, cacc, 0, 0, 0);
    }
    int col = 16 * n + r16;
    if (col < 100) {
      float bc = b2[col];
      int rowb = 16 * m + kg4 * 4;
#pragma unroll
      for (int reg = 0; reg < 4; ++reg) {
        int onode = blockIdx.x * 32 + rowb + reg;
        if (onode < N)
          out[(size_t)onode * 100 + col] = 1.f / (1.f + __expf(-(cacc[reg] + bc)));
      }
    }
  }
}

// ---------------------------------------------------------------------------

extern "C" void kernel_launch(void* const* d_in, const int* in_sizes, int n_in,
                              void* d_out, int out_size, void* d_ws, size_t ws_size,
                              hipStream_t stream) {
  const float* x    = (const float*)d_in[0];
  const int*   ei   = (const int*)d_in[1];    // harness converts integer inputs to int32
  const float* W1   = (const float*)d_in[2];
  const float* a_s1 = (const float*)d_in[3];
  const float* a_d1 = (const float*)d_in[4];
  const float* b1   = (const float*)d_in[5];
  const float* W2   = (const float*)d_in[6];
  const float* a_s2 = (const float*)d_in[7];
  const float* a_d2 = (const float*)d_in[8];
  const float* b2   = (const float*)d_in[9];
  float* out = (float*)d_out;

  const int N = in_sizes[0] / 256;
  const int E = in_sizes[1] / 2;
  const int K = (N + BNN - 1) >> BSH;       // buckets (<=256 for N<=131072)

  char* w = (char*)d_ws;
  size_t off = 0;
  auto alloc = [&](size_t bytes) -> char* {
    char* p = w + off;
    off = (off + bytes + 255) & ~(size_t)255;
    return p;
  };
  unsigned short* h1b    = (unsigned short*)alloc((size_t)N * 64 * 2);
  unsigned short* helu_b = (unsigned short*)alloc((size_t)N * 64 * 2);
  unsigned short* w1t    = (unsigned short*)alloc(64 * 256 * 2);
  unsigned short* w2t    = (unsigned short*)alloc(112 * 64 * 2);
  float* as1  = (float*)alloc((size_t)N * 8 * 4);
  float* ad1  = (float*)alloc((size_t)N * 8 * 4);
  float* as2  = (float*)alloc((size_t)N * 4);
  float* ad2  = (float*)alloc((size_t)N * 4);
  float* w2as = (float*)alloc(64 * 4);
  float* w2ad = (float*)alloc(64 * 4);
  int*   offs   = (int*)alloc((size_t)(N + 1) * 4);
  int*   csr    = (int*)alloc((size_t)(E + N) * 4);
  unsigned int* binned2 = (unsigned int*)alloc((size_t)K * SEG * 4);
  int*   bcur0  = (int*)alloc((size_t)K * 4);
  (void)ws_size; (void)n_in; (void)out_size;

  k_init<<<17, 256, 0, stream>>>(W1, w1t, W2, a_s2, a_d2, w2as, w2ad, w2t,
                                 bcur0, K, offs, N, E);

  const int ebl = (E + 2047) / 2048;
  const int totalG = (N + 31) / 32;
  const int GA = (totalG + 1) / 2;
  const int GB = totalG - GA;
  const int rowbase = GA * 32;

  k_g1bin<<<GA + ebl, 256, 0, stream>>>(x, w1t, a_s1, a_d1, h1b, as1, ad1, N, GA,
                                        ei, E, bcur0, binned2);
  k_g1bkt<<<GB + K, 256, 0, stream>>>(x, w1t, a_s1, a_d1, h1b, as1, ad1, N, rowbase, GB,
                                      bcur0, binned2, offs, csr, K);

  k_agg1<<<(N + 31) / 32, 256, 0, stream>>>(csr, offs, h1b, as1, ad1, b1, w2as, w2ad,
                                            helu_b, as2, ad2, N);
  k_agg2g<<<(N + 31) / 32, 256, 0, stream>>>(csr, offs, helu_b, as2, ad2, w2t, b2, out, N);
}

// Round 18
// 188.297 us; speedup vs baseline: 1.2860x; 1.0604x over previous
//
#include <hip/hip_runtime.h>
#include <hip/hip_bf16.h>
#include <cmath>

// ---------------------------------------------------------------------------
// GAT 2-layer forward.
// CSR build fully overlapped with gemm1 (k1=[gemm1A||bin], k2=[gemm1B||bucket]).
// Gather tables h1/helu stored INT8 (sym, range +-12, 64B rows -> 6.4MB tables,
// XCD-L2 resident; scale folded into 1/denom). Alphas fp32-exact. agg2g fuses
// aggregation + in-block MFMA GEMM (bf16 w2t) + bias + sigmoid.
// ---------------------------------------------------------------------------

#define BSH 9                 // 512 nodes per bucket; requires N <= 131072
#define BNN (1 << BSH)
#define SEG 12288             // per-bucket segment capacity (mean 8192, +45 sigma)
#define QR 12.0f              // int8 range
#define SC_ENC (127.0f / QR)
#define SC_DEC (QR / 127.0f)

typedef __attribute__((ext_vector_type(8))) short short8v;
typedef __attribute__((ext_vector_type(4))) float f32x4;

__device__ __forceinline__ float lrelu02(float v) { return v > 0.f ? v : 0.2f * v; }

__device__ __forceinline__ unsigned short f2b(float f) {
  union { float f; unsigned int i; } c; c.f = f;
  unsigned int r = c.i + 0x7FFFu + ((c.i >> 16) & 1u);   // RNE
  return (unsigned short)(r >> 16);
}
__device__ __forceinline__ float lo16(unsigned int u) {
  union { float f; unsigned int i; } c; c.i = u << 16; return c.f;
}
__device__ __forceinline__ float hi16(unsigned int u) {
  union { float f; unsigned int i; } c; c.i = u & 0xFFFF0000u; return c.f;
}
__device__ __forceinline__ signed char q8(float v) {
  v = fminf(fmaxf(v * SC_ENC, -127.f), 127.f);
  return (signed char)(int)rintf(v);
}
// decode byte j (0..3) of u as signed int -> float
__device__ __forceinline__ float d8(unsigned int u, int j) {
  return (float)((int)(u << (24 - 8 * j)) >> 24);
}

// ---- init: W1^T->bf16 (blocks 0-15); W2-proj + w2t bf16 + bcur0 (block 16) --

__global__ __launch_bounds__(256) void k_init(const float* __restrict__ W1,
                                              unsigned short* __restrict__ w1t,
                                              const float* __restrict__ W2,
                                              const float* __restrict__ a2s,
                                              const float* __restrict__ a2d,
                                              float* __restrict__ w2as, float* __restrict__ w2ad,
                                              unsigned short* __restrict__ w2t,
                                              int* __restrict__ bcur0, int K,
                                              int* __restrict__ offs, int N, int E) {
  int b = blockIdx.x, t = threadIdx.x;
  if (b < 16) {
    int idx = b * 256 + t;                    // 0..4095
#pragma unroll
    for (int j = 0; j < 4; ++j) {
      int e = idx * 4 + j;                    // flat w1t index = col*256 + k
      int col = e >> 8, k = e & 255;
      w1t[e] = f2b(W1[k * 64 + col]);
    }
  } else {
    if (t < K) bcur0[t] = 0;
    if (t == 255) offs[N] = E + N;
    if (t < 64) {
      float s = 0.f;
      for (int k = 0; k < 100; ++k) s += W2[t * 100 + k] * a2s[k];
      w2as[t] = s;
    } else if (t < 128) {
      int c = t - 64;
      float s = 0.f;
      for (int k = 0; k < 100; ++k) s += W2[c * 100 + k] * a2d[k];
      w2ad[c] = s;
    }
    // w2t[c][k] = bf16(W2[k][c]), c<112 (pad cols 100..111 with 0)
    for (int i = t; i < 112 * 64; i += 256) {
      int c = i >> 6, k = i & 63;
      w2t[i] = f2b(c < 100 ? W2[k * 100 + c] : 0.f);
    }
  }
}

// ---- shared gemm1 device body (32-row tile, B hoisted to registers) -------

__device__ __forceinline__ void gemm1_body(const float* __restrict__ x,
                                           const unsigned short* __restrict__ w1t,
                                           const float* __restrict__ av_s,
                                           const float* __restrict__ av_d,
                                           signed char* __restrict__ h1i,
                                           float* __restrict__ as1, float* __restrict__ ad1,
                                           int N, int row0, unsigned short* xs /*32*268*/) {
  int tid = threadIdx.x;
  int w = tid >> 6, lane = tid & 63;
  int wr = w & 1, wc = w >> 1;
  int r16 = lane & 15, kg4 = lane >> 4;
  const unsigned short* pw = &w1t[(32 * wc + r16) * 256 + kg4 * 8];
  short8v breg[8][2];
#pragma unroll
  for (int ks = 0; ks < 8; ++ks) {
#pragma unroll
    for (int f = 0; f < 2; ++f) {
      union { short8v s; uint4 u; } bv;
      bv.u = *(const uint4*)(pw + f * 16 * 256 + ks * 32);
      breg[ks][f] = bv.s;
    }
  }
#pragma unroll
  for (int it = 0; it < 4; ++it) {
    int slot = tid + it * 256;              // 0..1023
    int row = slot >> 5, kg = slot & 31;    // k-base = kg*8
    int grow = row0 + row;
    uint4 pk = make_uint4(0u, 0u, 0u, 0u);
    if (grow < N) {
      const float* px = &x[(size_t)grow * 256 + kg * 8];
      float4 v0 = *(const float4*)px;
      float4 v1 = *(const float4*)(px + 4);
      pk.x = f2b(v0.x) | ((unsigned)f2b(v0.y) << 16);
      pk.y = f2b(v0.z) | ((unsigned)f2b(v0.w) << 16);
      pk.z = f2b(v1.x) | ((unsigned)f2b(v1.y) << 16);
      pk.w = f2b(v1.z) | ((unsigned)f2b(v1.w) << 16);
    }
    *(uint4*)&xs[row * 268 + kg * 8] = pk;
  }
  __syncthreads();
  f32x4 acc[2];
  acc[0] = (f32x4){0.f, 0.f, 0.f, 0.f};
  acc[1] = (f32x4){0.f, 0.f, 0.f, 0.f};
  const unsigned short* xrow = &xs[(16 * wr + r16) * 268 + kg4 * 8];
#pragma unroll
  for (int ks = 0; ks < 8; ++ks) {
    short8v a = *(const short8v*)(xrow + ks * 32);
    acc[0] = __builtin_amdgcn_mfma_f32_16x16x32_bf16(a, breg[ks][0], acc[0], 0, 0, 0);
    acc[1] = __builtin_amdgcn_mfma_f32_16x16x32_bf16(a, breg[ks][1], acc[1], 0, 0, 0);
  }
  float avv[2], bvv[2];
#pragma unroll
  for (int f = 0; f < 2; ++f) {
    avv[f] = av_s[32 * wc + 16 * f + r16];
    bvv[f] = av_d[32 * wc + 16 * f + r16];
  }
  int rbase = row0 + 16 * wr + kg4 * 4;
#pragma unroll
  for (int reg = 0; reg < 4; ++reg) {
    int row = rbase + reg;
    bool ok = row < N;
    if (ok) {
#pragma unroll
      for (int f = 0; f < 2; ++f)
        h1i[(size_t)row * 64 + 32 * wc + 16 * f + r16] = q8(acc[f][reg]);
    }
    float ts[2], td[2];
#pragma unroll
    for (int f = 0; f < 2; ++f) { ts[f] = acc[f][reg] * avv[f]; td[f] = acc[f][reg] * bvv[f]; }
#pragma unroll
    for (int off = 1; off <= 4; off <<= 1) {
#pragma unroll
      for (int f = 0; f < 2; ++f) {
        ts[f] += __shfl_xor(ts[f], off);
        td[f] += __shfl_xor(td[f], off);
      }
    }
    if (ok && (r16 & 7) == 0) {
      int bsel = r16 >> 3;
#pragma unroll
      for (int f = 0; f < 2; ++f) {
        as1[row * 8 + 4 * wc + 2 * f + bsel] = ts[f];
        ad1[row * 8 + 4 * wc + 2 * f + bsel] = td[f];
      }
    }
  }
}

// ---- k1: gemm1 half A  ||  bin into per-bucket segments -------------------

__global__ __launch_bounds__(256) void k_g1bin(const float* __restrict__ x,
                                               const unsigned short* __restrict__ w1t,
                                               const float* __restrict__ av_s, const float* __restrict__ av_d,
                                               signed char* __restrict__ h1i,
                                               float* __restrict__ as1, float* __restrict__ ad1,
                                               int N, int GA,
                                               const int* __restrict__ ei, int E,
                                               int* __restrict__ bcur0, unsigned int* __restrict__ binned2) {
  __shared__ unsigned short xs[32 * 268];
  if ((int)blockIdx.x < GA) {
    gemm1_body(x, w1t, av_s, av_d, h1i, as1, ad1, N, blockIdx.x * 32, xs);
    return;
  }
  int* lh = (int*)xs;
  int* lbase = lh + 256;
  int tid = threadIdx.x;
  lh[tid] = 0;
  __syncthreads();
  int base = (blockIdx.x - GA) * 2048;
  int bj[8], rk[8];
  unsigned int pk[8];
#pragma unroll
  for (int j = 0; j < 8; ++j) {
    int e = base + j * 256 + tid;
    bj[j] = -1;
    if (e < E) {
      unsigned int sj = (unsigned int)ei[e];
      int d = ei[E + e];
      bj[j] = d >> BSH;
      pk[j] = sj | ((unsigned int)(d & (BNN - 1)) << 17);
      rk[j] = atomicAdd(&lh[bj[j]], 1);
    }
  }
  __syncthreads();
  if (lh[tid]) lbase[tid] = atomicAdd(&bcur0[tid], lh[tid]);
  __syncthreads();
#pragma unroll
  for (int j = 0; j < 8; ++j)
    if (bj[j] >= 0) binned2[(size_t)bj[j] * SEG + lbase[bj[j]] + rk[j]] = pk[j];
}

// ---- k2: gemm1 half B  ||  per-bucket CSR fill (in-block scan) ------------

__global__ __launch_bounds__(256) void k_g1bkt(const float* __restrict__ x,
                                               const unsigned short* __restrict__ w1t,
                                               const float* __restrict__ av_s, const float* __restrict__ av_d,
                                               signed char* __restrict__ h1i,
                                               float* __restrict__ as1, float* __restrict__ ad1,
                                               int N, int rowbase, int GB,
                                               const int* __restrict__ bcur0,
                                               const unsigned int* __restrict__ binned2,
                                               int* __restrict__ offs, int* __restrict__ csr, int K) {
  __shared__ unsigned short xs[32 * 268];
  if ((int)blockIdx.x < GB) {
    gemm1_body(x, w1t, av_s, av_d, h1i, as1, ad1, N, rowbase + blockIdx.x * 32, xs);
    return;
  }
  int* hist  = (int*)xs;            // [512]
  int* loffS = hist + BNN;          // [512]
  int* cur   = loffS + BNN;         // [512]
  int* s     = cur + BNN;           // [256]
  __shared__ int sh_e0, sh_cnt;
  int tid = threadIdx.x;
  int b = blockIdx.x - GB;
  int node0 = b << BSH;
  int sl = min(BNN, N - node0);
  int v = (tid < K) ? bcur0[tid] : 0;
  s[tid] = v;
  __syncthreads();
  for (int off = 1; off < 256; off <<= 1) {
    int t = (tid >= off) ? s[tid - off] : 0;
    __syncthreads();
    s[tid] += t;
    __syncthreads();
  }
  if (tid == b) { sh_e0 = s[tid] - v; sh_cnt = v; }
  __syncthreads();
  int e0 = sh_e0, cnt = sh_cnt;
  int cbase = e0 + min(node0, N);          // csr base incl. upstream self-loops
  const unsigned int* seg = &binned2[(size_t)b * SEG];
  hist[tid] = 0; hist[tid + 256] = 0;
  __syncthreads();
  for (int e = tid; e < cnt; e += 256) atomicAdd(&hist[seg[e] >> 17], 1);
  __syncthreads();
  int a0 = hist[2 * tid], a1 = hist[2 * tid + 1];
  s[tid] = a0 + a1;
  __syncthreads();
  for (int off = 1; off < 256; off <<= 1) {
    int t = (tid >= off) ? s[tid - off] : 0;
    __syncthreads();
    s[tid] += t;
    __syncthreads();
  }
  int excl = s[tid] - (a0 + a1);
  loffS[2 * tid]     = excl + 2 * tid;
  loffS[2 * tid + 1] = excl + a0 + 2 * tid + 1;
  __syncthreads();
  cur[2 * tid] = loffS[2 * tid];
  cur[2 * tid + 1] = loffS[2 * tid + 1];
  if (2 * tid < sl)     offs[node0 + 2 * tid]     = cbase + loffS[2 * tid];
  if (2 * tid + 1 < sl) offs[node0 + 2 * tid + 1] = cbase + loffS[2 * tid + 1];
  __syncthreads();
  for (int e = tid; e < cnt; e += 256) {
    unsigned int u = seg[e];
    int p = atomicAdd(&cur[u >> 17], 1);
    csr[cbase + p] = (int)(u & 0x1FFFFu);
  }
  for (int i = tid; i < sl; i += 256) {
    int p = atomicAdd(&cur[i], 1);
    csr[cbase + p] = node0 + i;            // self loop
  }
}

// ---- Layer 1 aggregate: 8 nodes/wave, 8 lanes/node, int8 gather -----------

__global__ __launch_bounds__(256) void k_agg1(const int* __restrict__ csr, const int* __restrict__ offs,
                                              const signed char* __restrict__ h1i,
                                              const float* __restrict__ as1, const float* __restrict__ ad1,
                                              const float* __restrict__ b1,
                                              const float* __restrict__ w2as, const float* __restrict__ w2ad,
                                              signed char* __restrict__ helu_i,
                                              float* __restrict__ as2, float* __restrict__ ad2, int N) {
  __shared__ float wsm[4][8][8][9];   // [wave][sub][head][edge(pad 9)]
  int tid = threadIdx.x;
  int w = tid >> 6, lane = tid & 63;
  int sub = lane >> 3, q = lane & 7;
  int base = sub << 3;                // first lane of this sub-group
  int node = blockIdx.x * 32 + w * 8 + sub;
  bool valid = node < N;
  int beg = 0, end = 0;
  if (valid) { beg = offs[node]; end = offs[node + 1]; }
  int deg = end - beg;
  int dm = deg;
  dm = max(dm, __shfl_xor(dm, 8));
  dm = max(dm, __shfl_xor(dm, 16));
  dm = max(dm, __shfl_xor(dm, 32));
  float4 advlo = make_float4(0.f, 0.f, 0.f, 0.f), advhi = advlo;
  if (valid) {
    advlo = *(const float4*)&ad1[node * 8];
    advhi = *(const float4*)&ad1[node * 8 + 4];
  }
  float denom = 0.f;
  float4 acc0 = make_float4(0.f, 0.f, 0.f, 0.f);
  float4 acc1 = make_float4(0.f, 0.f, 0.f, 0.f);
  for (int c0 = 0; c0 < dm; c0 += 8) {
    int cn = min(8, deg - c0);          // may be <= 0 for finished nodes
    int sreg = 0;
    if (q < cn) {
      sreg = csr[beg + c0 + q];
      float4 alo = *(const float4*)&as1[sreg * 8];
      float4 ahi = *(const float4*)&as1[sreg * 8 + 4];
      wsm[w][sub][0][q] = __expf(lrelu02(alo.x + advlo.x));
      wsm[w][sub][1][q] = __expf(lrelu02(alo.y + advlo.y));
      wsm[w][sub][2][q] = __expf(lrelu02(alo.z + advlo.z));
      wsm[w][sub][3][q] = __expf(lrelu02(alo.w + advlo.w));
      wsm[w][sub][4][q] = __expf(lrelu02(ahi.x + advhi.x));
      wsm[w][sub][5][q] = __expf(lrelu02(ahi.y + advhi.y));
      wsm[w][sub][6][q] = __expf(lrelu02(ahi.z + advhi.z));
      wsm[w][sub][7][q] = __expf(lrelu02(ahi.w + advhi.w));
    }
    int i = 0;
    for (; i + 2 <= cn; i += 2) {
      int s0 = __shfl(sreg, base + i);
      int s1 = __shfl(sreg, base + i + 1);
      float w0 = wsm[w][sub][q][i];
      float w1 = wsm[w][sub][q][i + 1];
      uint2 p0 = *(const uint2*)&h1i[(unsigned)s0 * 64 + q * 8];
      uint2 p1 = *(const uint2*)&h1i[(unsigned)s1 * 64 + q * 8];
      denom += w0 + w1;
      acc0.x += w0 * d8(p0.x, 0); acc0.y += w0 * d8(p0.x, 1);
      acc0.z += w0 * d8(p0.x, 2); acc0.w += w0 * d8(p0.x, 3);
      acc1.x += w0 * d8(p0.y, 0); acc1.y += w0 * d8(p0.y, 1);
      acc1.z += w0 * d8(p0.y, 2); acc1.w += w0 * d8(p0.y, 3);
      acc0.x += w1 * d8(p1.x, 0); acc0.y += w1 * d8(p1.x, 1);
      acc0.z += w1 * d8(p1.x, 2); acc0.w += w1 * d8(p1.x, 3);
      acc1.x += w1 * d8(p1.y, 0); acc1.y += w1 * d8(p1.y, 1);
      acc1.z += w1 * d8(p1.y, 2); acc1.w += w1 * d8(p1.y, 3);
    }
    if (i < cn) {
      int s0 = __shfl(sreg, base + i);
      float w0 = wsm[w][sub][q][i];
      uint2 p0 = *(const uint2*)&h1i[(unsigned)s0 * 64 + q * 8];
      denom += w0;
      acc0.x += w0 * d8(p0.x, 0); acc0.y += w0 * d8(p0.x, 1);
      acc0.z += w0 * d8(p0.x, 2); acc0.w += w0 * d8(p0.x, 3);
      acc1.x += w0 * d8(p0.y, 0); acc1.y += w0 * d8(p0.y, 1);
      acc1.z += w0 * d8(p0.y, 2); acc1.w += w0 * d8(p0.y, 3);
    }
  }
  // epilogue: rd folds int8 decode scale
  float rd = SC_DEC / denom;
  float4 ba = valid ? *(const float4*)&b1[q * 8] : make_float4(0.f, 0.f, 0.f, 0.f);
  float4 bb = valid ? *(const float4*)&b1[q * 8 + 4] : make_float4(0.f, 0.f, 0.f, 0.f);
  float o[8];
  o[0] = acc0.x * rd + ba.x; o[1] = acc0.y * rd + ba.y;
  o[2] = acc0.z * rd + ba.z; o[3] = acc0.w * rd + ba.w;
  o[4] = acc1.x * rd + bb.x; o[5] = acc1.y * rd + bb.y;
  o[6] = acc1.z * rd + bb.z; o[7] = acc1.w * rd + bb.w;
#pragma unroll
  for (int j = 0; j < 8; ++j) o[j] = o[j] > 0.f ? o[j] : __expf(o[j]) - 1.f;  // ELU
  if (valid) {
    int c0i = (int)(unsigned char)q8(o[0]), c1i = (int)(unsigned char)q8(o[1]);
    int c2i = (int)(unsigned char)q8(o[2]), c3i = (int)(unsigned char)q8(o[3]);
    int c4i = (int)(unsigned char)q8(o[4]), c5i = (int)(unsigned char)q8(o[5]);
    int c6i = (int)(unsigned char)q8(o[6]), c7i = (int)(unsigned char)q8(o[7]);
    uint2 ob;
    ob.x = (unsigned)c0i | ((unsigned)c1i << 8) | ((unsigned)c2i << 16) | ((unsigned)c3i << 24);
    ob.y = (unsigned)c4i | ((unsigned)c5i << 8) | ((unsigned)c6i << 16) | ((unsigned)c7i << 24);
    *(uint2*)&helu_i[(size_t)node * 64 + q * 8] = ob;
  }
  // fused layer-2 alpha projection (reduce over the 8 lanes of the node)
  float s2 = 0.f, d2 = 0.f;
  if (valid) {
    float4 wa0 = *(const float4*)&w2as[q * 8];
    float4 wa1 = *(const float4*)&w2as[q * 8 + 4];
    float4 wd0 = *(const float4*)&w2ad[q * 8];
    float4 wd1 = *(const float4*)&w2ad[q * 8 + 4];
    s2 = o[0] * wa0.x + o[1] * wa0.y + o[2] * wa0.z + o[3] * wa0.w
       + o[4] * wa1.x + o[5] * wa1.y + o[6] * wa1.z + o[7] * wa1.w;
    d2 = o[0] * wd0.x + o[1] * wd0.y + o[2] * wd0.z + o[3] * wd0.w
       + o[4] * wd1.x + o[5] * wd1.y + o[6] * wd1.z + o[7] * wd1.w;
  }
#pragma unroll
  for (int off = 1; off <= 4; off <<= 1) {
    s2 += __shfl_xor(s2, off);
    d2 += __shfl_xor(d2, off);
  }
  if (valid && q == 0) { as2[node] = s2; ad2[node] = d2; }
}

// ---- Layer 2 aggregate (int8 gather) + fused final GEMM + sigmoid ---------

__global__ __launch_bounds__(256) void k_agg2g(const int* __restrict__ csr, const int* __restrict__ offs,
                                               const signed char* __restrict__ helu_i,
                                               const float* __restrict__ as2, const float* __restrict__ ad2,
                                               const unsigned short* __restrict__ w2t,
                                               const float* __restrict__ b2,
                                               float* __restrict__ out, int N) {
  __shared__ unsigned short aggl[32 * 68];   // [node_in_block][ch], pad 68
  int tid = threadIdx.x;
  int w = tid >> 6, lane = tid & 63;
  int sub = lane >> 3, q = lane & 7;
  int base = sub << 3;
  int nb = w * 8 + sub;
  int node = blockIdx.x * 32 + nb;
  bool valid = node < N;
  int beg = 0, end = 0;
  if (valid) { beg = offs[node]; end = offs[node + 1]; }
  int deg = end - beg;
  int dm = deg;
  dm = max(dm, __shfl_xor(dm, 8));
  dm = max(dm, __shfl_xor(dm, 16));
  dm = max(dm, __shfl_xor(dm, 32));
  float adv = valid ? ad2[node] : 0.f;
  float denom = 0.f;
  float4 acc0 = make_float4(0.f, 0.f, 0.f, 0.f);
  float4 acc1 = make_float4(0.f, 0.f, 0.f, 0.f);
  for (int c0 = 0; c0 < dm; c0 += 8) {
    int cn = min(8, deg - c0);
    int sreg = 0; float wq = 0.f;
    if (q < cn) {
      sreg = csr[beg + c0 + q];
      wq = __expf(lrelu02(as2[sreg] + adv));
    }
    int i = 0;
    for (; i + 2 <= cn; i += 2) {
      int s0 = __shfl(sreg, base + i);
      int s1 = __shfl(sreg, base + i + 1);
      float w0 = __shfl(wq, base + i);
      float w1 = __shfl(wq, base + i + 1);
      uint2 p0 = *(const uint2*)&helu_i[(unsigned)s0 * 64 + q * 8];
      uint2 p1 = *(const uint2*)&helu_i[(unsigned)s1 * 64 + q * 8];
      denom += w0 + w1;
      acc0.x += w0 * d8(p0.x, 0); acc0.y += w0 * d8(p0.x, 1);
      acc0.z += w0 * d8(p0.x, 2); acc0.w += w0 * d8(p0.x, 3);
      acc1.x += w0 * d8(p0.y, 0); acc1.y += w0 * d8(p0.y, 1);
      acc1.z += w0 * d8(p0.y, 2); acc1.w += w0 * d8(p0.y, 3);
      acc0.x += w1 * d8(p1.x, 0); acc0.y += w1 * d8(p1.x, 1);
      acc0.z += w1 * d8(p1.x, 2); acc0.w += w1 * d8(p1.x, 3);
      acc1.x += w1 * d8(p1.y, 0); acc1.y += w1 * d8(p1.y, 1);
      acc1.z += w1 * d8(p1.y, 2); acc1.w += w1 * d8(p1.y, 3);
    }
    if (i < cn) {
      int s0 = __shfl(sreg, base + i);
      float w0 = __shfl(wq, base + i);
      uint2 p0 = *(const uint2*)&helu_i[(unsigned)s0 * 64 + q * 8];
      denom += w0;
      acc0.x += w0 * d8(p0.x, 0); acc0.y += w0 * d8(p0.x, 1);
      acc0.z += w0 * d8(p0.x, 2); acc0.w += w0 * d8(p0.x, 3);
      acc1.x += w0 * d8(p0.y, 0); acc1.y += w0 * d8(p0.y, 1);
      acc1.z += w0 * d8(p0.y, 2); acc1.w += w0 * d8(p0.y, 3);
    }
  }
  // stage bf16 aggregate into LDS (rd folds int8 scale; invalid rows unused)
  float rd = valid ? (SC_DEC / denom) : 0.f;
  uint4 ob;
  ob.x = f2b(acc0.x * rd) | ((unsigned)f2b(acc0.y * rd) << 16);
  ob.y = f2b(acc0.z * rd) | ((unsigned)f2b(acc0.w * rd) << 16);
  ob.z = f2b(acc1.x * rd) | ((unsigned)f2b(acc1.y * rd) << 16);
  ob.w = f2b(acc1.z * rd) | ((unsigned)f2b(acc1.w * rd) << 16);
  *(uint4*)&aggl[nb * 68 + q * 8] = ob;
  __syncthreads();
  // mini-GEMM: C-tile t (m=t&1, n=t>>1); wave w does t = w, w+4, w+8, w+12
  int r16 = lane & 15, kg4 = lane >> 4;
#pragma unroll
  for (int tt = 0; tt < 4; ++tt) {
    int t = w + tt * 4;
    if (t >= 14) break;
    int m = t & 1, n = t >> 1;
    f32x4 cacc = (f32x4){0.f, 0.f, 0.f, 0.f};
#pragma unroll
    for (int ks = 0; ks < 2; ++ks) {
      short8v a = *(const short8v*)&aggl[(16 * m + r16) * 68 + ks * 32 + kg4 * 8];
      short8v b = *(const short8v*)&w2t[(16 * n + r16) * 64 + ks * 32 + kg4 * 8];
      cacc = __builtin_amdgcn_mfma_f32_16x16x32_bf16(a, b, cacc, 0, 0, 0);
    }
    int col = 16 * n + r16;
    if (col < 100) {
      float bc = b2[col];
      int rowb = 16 * m + kg4 * 4;
#pragma unroll
      for (int reg = 0; reg < 4; ++reg) {
        int onode = blockIdx.x * 32 + rowb + reg;
        if (onode < N)
          out[(size_t)onode * 100 + col] = 1.f / (1.f + __expf(-(cacc[reg] + bc)));
      }
    }
  }
}

// ---------------------------------------------------------------------------

extern "C" void kernel_launch(void* const* d_in, const int* in_sizes, int n_in,
                              void* d_out, int out_size, void* d_ws, size_t ws_size,
                              hipStream_t stream) {
  const float* x    = (const float*)d_in[0];
  const int*   ei   = (const int*)d_in[1];    // harness converts integer inputs to int32
  const float* W1   = (const float*)d_in[2];
  const float* a_s1 = (const float*)d_in[3];
  const float* a_d1 = (const float*)d_in[4];
  const float* b1   = (const float*)d_in[5];
  const float* W2   = (const float*)d_in[6];
  const float* a_s2 = (const float*)d_in[7];
  const float* a_d2 = (const float*)d_in[8];
  const float* b2   = (const float*)d_in[9];
  float* out = (float*)d_out;

  const int N = in_sizes[0] / 256;
  const int E = in_sizes[1] / 2;
  const int K = (N + BNN - 1) >> BSH;       // buckets (<=256 for N<=131072)

  char* w = (char*)d_ws;
  size_t off = 0;
  auto alloc = [&](size_t bytes) -> char* {
    char* p = w + off;
    off = (off + bytes + 255) & ~(size_t)255;
    return p;
  };
  signed char* h1i    = (signed char*)alloc((size_t)N * 64);
  signed char* helu_i = (signed char*)alloc((size_t)N * 64);
  unsigned short* w1t = (unsigned short*)alloc(64 * 256 * 2);
  unsigned short* w2t = (unsigned short*)alloc(112 * 64 * 2);
  float* as1  = (float*)alloc((size_t)N * 8 * 4);
  float* ad1  = (float*)alloc((size_t)N * 8 * 4);
  float* as2  = (float*)alloc((size_t)N * 4);
  float* ad2  = (float*)alloc((size_t)N * 4);
  float* w2as = (float*)alloc(64 * 4);
  float* w2ad = (float*)alloc(64 * 4);
  int*   offs   = (int*)alloc((size_t)(N + 1) * 4);
  int*   csr    = (int*)alloc((size_t)(E + N) * 4);
  unsigned int* binned2 = (unsigned int*)alloc((size_t)K * SEG * 4);
  int*   bcur0  = (int*)alloc((size_t)K * 4);
  (void)ws_size; (void)n_in; (void)out_size;

  k_init<<<17, 256, 0, stream>>>(W1, w1t, W2, a_s2, a_d2, w2as, w2ad, w2t,
                                 bcur0, K, offs, N, E);

  const int ebl = (E + 2047) / 2048;
  const int totalG = (N + 31) / 32;
  const int GA = (totalG + 1) / 2;
  const int GB = totalG - GA;
  const int rowbase = GA * 32;

  k_g1bin<<<GA + ebl, 256, 0, stream>>>(x, w1t, a_s1, a_d1, h1i, as1, ad1, N, GA,
                                        ei, E, bcur0, binned2);
  k_g1bkt<<<GB + K, 256, 0, stream>>>(x, w1t, a_s1, a_d1, h1i, as1, ad1, N, rowbase, GB,
                                      bcur0, binned2, offs, csr, K);

  k_agg1<<<(N + 31) / 32, 256, 0, stream>>>(csr, offs, h1i, as1, ad1, b1, w2as, w2ad,
                                            helu_i, as2, ad2, N);
  k_agg2g<<<(N + 31) / 32, 256, 0, stream>>>(csr, offs, helu_i, as2, ad2, w2t, b2, out, N);
}